// Round 1
// baseline (4529.263 us; speedup 1.0000x reference)
//
#include <hip/hip_runtime.h>

// ---- problem constants (match reference) ----
namespace {
constexpr int NN   = 100000;  // nodes
constexpr int RR   = 3;       // relations
constexpr int EE   = 500000;  // edges per relation
constexpr int FIN  = 256;
constexpr int FHID = 128;
constexpr int FOUT = 64;
}

// ---------------- degree kernels ----------------
__global__ __launch_bounds__(256) void deg_count_kernel(
    const int* __restrict__ src, const int* __restrict__ dst,
    float* __restrict__ s_out, float* __restrict__ s_in)
{
    int idx = blockIdx.x * 256 + threadIdx.x;
    if (idx >= RR * EE) return;
    int r = idx / EE;
    atomicAdd(&s_out[(size_t)r * NN + src[idx]], 1.0f);
    atomicAdd(&s_in [(size_t)r * NN + dst[idx]], 1.0f);
}

__global__ __launch_bounds__(256) void deg_finalize_kernel(float* __restrict__ s)
{
    int idx = blockIdx.x * 256 + threadIdx.x;
    if (idx >= 2 * RR * NN) return;
    float d = s[idx];
    s[idx] = 1.0f / sqrtf(fmaxf(d, 1.0f));
}

// ---------------- GEMM: C[N,M] = A[N,K] @ B[K,M] (f32, vector ALU) ----------------
template<int K, int M>
__global__ __launch_bounds__(256) void gemm_kernel(
    const float* __restrict__ A, const float* __restrict__ B,
    float* __restrict__ C, int N)
{
    constexpr int BM = 64;
    constexpr int BK = 32;
    constexpr int TN = 4;
    constexpr int CT = M / TN;        // col-thread count: 32 (M=128) / 16 (M=64)
    constexpr int RT = 256 / CT;      // row-thread count: 8 / 16
    constexpr int TM = BM / RT;       // rows per thread: 8 / 4
    constexpr int AS_STRIDE = BM + 4; // 68 floats = 272B: 16B-aligned rows, breaks bank conflicts

    __shared__ float As[BK][AS_STRIDE]; // transposed A tile: As[k][row]
    __shared__ float Bs[BK][M];

    const int tid  = threadIdx.x;
    const int row0 = blockIdx.x * BM;
    const int ct   = tid % CT;
    const int rt   = tid / CT;

    float acc[TM][TN];
    #pragma unroll
    for (int i = 0; i < TM; ++i)
        #pragma unroll
        for (int j = 0; j < TN; ++j) acc[i][j] = 0.0f;

    for (int k0 = 0; k0 < K; k0 += BK) {
        // stage A tile (64 rows x 32 k), store transposed
        #pragma unroll
        for (int l = 0; l < 2; ++l) {
            int t  = tid + l * 256;       // 0..511
            int r  = t >> 3;              // row within tile (BK/4 = 8 vec4 per row)
            int kv = t & 7;
            int gr = row0 + r;
            float4 v = make_float4(0.f, 0.f, 0.f, 0.f);
            if (gr < N)
                v = *reinterpret_cast<const float4*>(&A[(size_t)gr * K + k0 + kv * 4]);
            As[kv * 4 + 0][r] = v.x;
            As[kv * 4 + 1][r] = v.y;
            As[kv * 4 + 2][r] = v.z;
            As[kv * 4 + 3][r] = v.w;
        }
        // stage B tile (32 k x M)
        #pragma unroll
        for (int l = 0; l < (BK * M) / 1024; ++l) {
            int t  = tid + l * 256;
            int m4 = t % (M / 4);
            int kr = t / (M / 4);
            float4 v = *reinterpret_cast<const float4*>(&B[(size_t)(k0 + kr) * M + m4 * 4]);
            *reinterpret_cast<float4*>(&Bs[kr][m4 * 4]) = v;
        }
        __syncthreads();

        #pragma unroll
        for (int kk = 0; kk < BK; ++kk) {
            float bv[TN];
            #pragma unroll
            for (int j = 0; j < TN; ++j) bv[j] = Bs[kk][ct * TN + j];
            #pragma unroll
            for (int i = 0; i < TM; ++i) {
                float av = As[kk][rt * TM + i];
                #pragma unroll
                for (int j = 0; j < TN; ++j)
                    acc[i][j] = fmaf(av, bv[j], acc[i][j]);
            }
        }
        __syncthreads();
    }

    #pragma unroll
    for (int i = 0; i < TM; ++i) {
        int gr = row0 + rt * TM + i;
        if (gr < N) {
            float4 v = make_float4(acc[i][0], acc[i][1], acc[i][2], acc[i][3]);
            *reinterpret_cast<float4*>(&C[(size_t)gr * M + ct * TN]) = v;
        }
    }
}

// ---------------- edge scatter: agg[dst] += s_out[src] * Y[src] ----------------
template<int F>
__global__ __launch_bounds__(256) void scatter_kernel(
    const float* __restrict__ Y, const float* __restrict__ s_out,
    const int* __restrict__ src, const int* __restrict__ dst,
    float* __restrict__ agg)
{
    constexpr int TPE = F / 4;                   // threads per edge
    int idx = blockIdx.x * 256 + threadIdx.x;    // grid sized exactly: E*TPE
    int e = idx / TPE;
    int j = (idx % TPE) * 4;
    int s = src[e];
    int d = dst[e];
    float sc = s_out[s];
    float4 v = *reinterpret_cast<const float4*>(&Y[(size_t)s * F + j]);
    float* o = &agg[(size_t)d * F + j];
    atomicAdd(o + 0, sc * v.x);
    atomicAdd(o + 1, sc * v.y);
    atomicAdd(o + 2, sc * v.z);
    atomicAdd(o + 3, sc * v.w);
}

// ---------------- per-relation transform + mean/relu accumulation ----------------
// mode 0: h = val ; mode 1: h += val ; mode 2: h = (h + val)/R (+relu)
template<int F>
__global__ __launch_bounds__(256) void transform_kernel(
    const float* __restrict__ agg, const float* __restrict__ s_in,
    const float* __restrict__ b, float* __restrict__ h,
    int mode, int relu)
{
    constexpr int PV = F / 4;
    int idx = blockIdx.x * 256 + threadIdx.x;    // grid exact: N*PV
    if (idx >= NN * PV) return;
    int n = idx / PV;
    int j = (idx % PV) * 4;
    float si = s_in[n];
    float4 v  = *reinterpret_cast<const float4*>(&agg[(size_t)n * F + j]);
    float4 bb = *reinterpret_cast<const float4*>(&b[j]);
    float4 o;
    o.x = fmaf(v.x, si, bb.x);
    o.y = fmaf(v.y, si, bb.y);
    o.z = fmaf(v.z, si, bb.z);
    o.w = fmaf(v.w, si, bb.w);
    float4* hp = reinterpret_cast<float4*>(&h[(size_t)n * F + j]);
    if (mode >= 1) {
        float4 p = *hp;
        o.x += p.x; o.y += p.y; o.z += p.z; o.w += p.w;
    }
    if (mode == 2) {
        const float inv = 1.0f / (float)RR;
        o.x *= inv; o.y *= inv; o.z *= inv; o.w *= inv;
        if (relu) {
            o.x = fmaxf(o.x, 0.f);
            o.y = fmaxf(o.y, 0.f);
            o.z = fmaxf(o.z, 0.f);
            o.w = fmaxf(o.w, 0.f);
        }
    }
    *hp = o;
}

// ---------------- edge dot-product scores ----------------
__global__ __launch_bounds__(256) void score_kernel(
    const float* __restrict__ h, const int* __restrict__ src0,
    const int* __restrict__ dst0, const int* __restrict__ nsrc,
    const int* __restrict__ ndst, float* __restrict__ out)
{
    int idx = blockIdx.x * 256 + threadIdx.x;  // grid exact: 2*E*16
    int e = idx >> 4;
    int l = idx & 15;
    int u, v;
    if (e < EE) { u = src0[e]; v = dst0[e]; }
    else        { u = nsrc[e - EE]; v = ndst[e - EE]; }
    float4 a  = *reinterpret_cast<const float4*>(&h[(size_t)u * FOUT + l * 4]);
    float4 bb = *reinterpret_cast<const float4*>(&h[(size_t)v * FOUT + l * 4]);
    float p = a.x * bb.x + a.y * bb.y + a.z * bb.z + a.w * bb.w;
    p += __shfl_xor(p, 8, 16);
    p += __shfl_xor(p, 4, 16);
    p += __shfl_xor(p, 2, 16);
    p += __shfl_xor(p, 1, 16);
    if (l == 0) out[e] = p;
}

// ---------------- launch ----------------
extern "C" void kernel_launch(void* const* d_in, const int* in_sizes, int n_in,
                              void* d_out, int out_size, void* d_ws, size_t ws_size,
                              hipStream_t stream)
{
    const float* feature = (const float*)d_in[0];
    const float* W1      = (const float*)d_in[1];
    const float* b1      = (const float*)d_in[2];
    const float* W2      = (const float*)d_in[3];
    const float* b2      = (const float*)d_in[4];
    const int*   src     = (const int*)d_in[5];
    const int*   dst     = (const int*)d_in[6];
    const int*   nsrc    = (const int*)d_in[7];
    const int*   ndst    = (const int*)d_in[8];
    float* out = (float*)d_out;

    // workspace layout (floats): 45.4M total = 181.6 MB
    float* ws    = (float*)d_ws;
    float* s_out = ws;                          // R*N
    float* s_in  = s_out + (size_t)RR * NN;     // R*N
    float* h1    = s_in  + (size_t)RR * NN;     // N*128
    float* h2    = h1    + (size_t)NN * FHID;   // N*64
    float* Y     = h2    + (size_t)NN * FOUT;   // N*128 (reused both layers)
    float* agg   = Y     + (size_t)NN * FHID;   // N*128 (reused both layers)

    // degrees (shared by both layers)
    hipMemsetAsync(s_out, 0, sizeof(float) * 2 * RR * NN, stream);
    deg_count_kernel<<<(RR * EE + 255) / 256, 256, 0, stream>>>(src, dst, s_out, s_in);
    deg_finalize_kernel<<<(2 * RR * NN + 255) / 256, 256, 0, stream>>>(s_out);

    const int gemm_grid = (NN + 63) / 64;

    // ---- layer 1: h1 = relu(mean_r(scatter(feature@W1_r) * s_in + b1_r)) ----
    for (int r = 0; r < RR; ++r) {
        gemm_kernel<FIN, FHID><<<gemm_grid, 256, 0, stream>>>(
            feature, W1 + (size_t)r * FIN * FHID, Y, NN);
        hipMemsetAsync(agg, 0, sizeof(float) * (size_t)NN * FHID, stream);
        scatter_kernel<FHID><<<(EE * (FHID / 4)) / 256, 256, 0, stream>>>(
            Y, s_out + (size_t)r * NN, src + (size_t)r * EE, dst + (size_t)r * EE, agg);
        int mode = (r == 0) ? 0 : ((r == RR - 1) ? 2 : 1);
        transform_kernel<FHID><<<(NN * (FHID / 4) + 255) / 256, 256, 0, stream>>>(
            agg, s_in + (size_t)r * NN, b1 + (size_t)r * FHID, h1, mode, 1);
    }

    // ---- layer 2: h2 = mean_r(scatter(h1@W2_r) * s_in + b2_r) ----
    for (int r = 0; r < RR; ++r) {
        gemm_kernel<FHID, FOUT><<<gemm_grid, 256, 0, stream>>>(
            h1, W2 + (size_t)r * FHID * FOUT, Y, NN);
        hipMemsetAsync(agg, 0, sizeof(float) * (size_t)NN * FOUT, stream);
        scatter_kernel<FOUT><<<(EE * (FOUT / 4)) / 256, 256, 0, stream>>>(
            Y, s_out + (size_t)r * NN, src + (size_t)r * EE, dst + (size_t)r * EE, agg);
        int mode = (r == 0) ? 0 : ((r == RR - 1) ? 2 : 1);
        transform_kernel<FOUT><<<(NN * (FOUT / 4) + 255) / 256, 256, 0, stream>>>(
            agg, s_in + (size_t)r * NN, b2 + (size_t)r * FOUT, h2, mode, 0);
    }

    // ---- scores ----
    score_kernel<<<(2 * EE * 16) / 256, 256, 0, stream>>>(h2, src, dst, nsrc, ndst, out);
}

// Round 2
// 1226.856 us; speedup vs baseline: 3.6918x; 3.6918x over previous
//
#include <hip/hip_runtime.h>

// ---- problem constants (match reference) ----
namespace {
constexpr int NN   = 100000;  // nodes
constexpr int RR   = 3;       // relations
constexpr int EE   = 500000;  // edges per relation
constexpr int FIN  = 256;
constexpr int FHID = 128;
constexpr int FOUT = 64;
}

// ---------------- degree count (int atomics, L2-resident) ----------------
__global__ __launch_bounds__(256) void count_deg_kernel(
    const int* __restrict__ src, const int* __restrict__ dst,
    int* __restrict__ deg_out, int* __restrict__ deg_in)
{
    int idx = blockIdx.x * 256 + threadIdx.x;
    if (idx >= RR * EE) return;
    int r = idx / EE;
    atomicAdd(&deg_out[(size_t)r * NN + src[idx]], 1);
    atomicAdd(&deg_in [(size_t)r * NN + dst[idx]], 1);
}

__global__ __launch_bounds__(256) void finalize_deg_kernel(
    const int* __restrict__ deg_out, const int* __restrict__ deg_in,
    float* __restrict__ s_out, float* __restrict__ s_in)
{
    int idx = blockIdx.x * 256 + threadIdx.x;
    if (idx >= RR * NN) return;
    s_out[idx] = rsqrtf((float)max(deg_out[idx], 1));
    s_in [idx] = rsqrtf((float)max(deg_in [idx], 1));
}

// ---------------- exclusive scan of in-degrees -> row_ptr (1 block / relation) ----------------
__global__ __launch_bounds__(1024) void scan_kernel(
    const int* __restrict__ deg_in, int* __restrict__ row_ptr)
{
    const int r = blockIdx.x;
    const int t = threadIdx.x;
    const int* deg = deg_in + (size_t)r * NN;
    int* rp = row_ptr + (size_t)r * (NN + 1);
    constexpr int CHUNK = (NN + 1023) / 1024;   // 98

    __shared__ int sh[1024];
    int base = t * CHUNK;
    int own = 0;
    for (int i = 0; i < CHUNK; ++i) {
        int n = base + i;
        if (n < NN) own += deg[n];
    }
    sh[t] = own;
    __syncthreads();
    // Hillis-Steele inclusive scan over 1024 partials
    for (int off = 1; off < 1024; off <<= 1) {
        int v = 0;
        if (t >= off) v = sh[t - off];
        __syncthreads();
        if (t >= off) sh[t] += v;
        __syncthreads();
    }
    int run = sh[t] - own;   // exclusive prefix for this thread's chunk
    for (int i = 0; i < CHUNK; ++i) {
        int n = base + i;
        if (n < NN) { rp[n] = run; run += deg[n]; }
    }
    if (t == 1023) rp[NN] = EE;
}

// ---------------- CSR fill: col[] = src ids grouped by dst ----------------
__global__ __launch_bounds__(256) void fill_kernel(
    const int* __restrict__ src, const int* __restrict__ dst,
    const int* __restrict__ row_ptr, int* __restrict__ fill,
    int* __restrict__ col)
{
    int idx = blockIdx.x * 256 + threadIdx.x;
    if (idx >= RR * EE) return;
    int r = idx / EE;
    int d = dst[idx];
    int pos = row_ptr[(size_t)r * (NN + 1) + d] + atomicAdd(&fill[(size_t)r * NN + d], 1);
    col[(size_t)r * EE + pos] = src[idx];
}

// ---------------- GEMM: C[N,M] = A[N,K] @ B[K,M] (f32, vector ALU) ----------------
template<int K, int M>
__global__ __launch_bounds__(256) void gemm_kernel(
    const float* __restrict__ A, const float* __restrict__ B,
    float* __restrict__ C, int N)
{
    constexpr int BM = 64;
    constexpr int BK = 32;
    constexpr int TN = 4;
    constexpr int CT = M / TN;
    constexpr int RT = 256 / CT;
    constexpr int TM = BM / RT;
    constexpr int AS_STRIDE = BM + 4;

    __shared__ float As[BK][AS_STRIDE];
    __shared__ float Bs[BK][M];

    const int tid  = threadIdx.x;
    const int row0 = blockIdx.x * BM;
    const int ct   = tid % CT;
    const int rt   = tid / CT;

    float acc[TM][TN];
    #pragma unroll
    for (int i = 0; i < TM; ++i)
        #pragma unroll
        for (int j = 0; j < TN; ++j) acc[i][j] = 0.0f;

    for (int k0 = 0; k0 < K; k0 += BK) {
        #pragma unroll
        for (int l = 0; l < 2; ++l) {
            int t  = tid + l * 256;
            int r  = t >> 3;
            int kv = t & 7;
            int gr = row0 + r;
            float4 v = make_float4(0.f, 0.f, 0.f, 0.f);
            if (gr < N)
                v = *reinterpret_cast<const float4*>(&A[(size_t)gr * K + k0 + kv * 4]);
            As[kv * 4 + 0][r] = v.x;
            As[kv * 4 + 1][r] = v.y;
            As[kv * 4 + 2][r] = v.z;
            As[kv * 4 + 3][r] = v.w;
        }
        #pragma unroll
        for (int l = 0; l < (BK * M) / 1024; ++l) {
            int t  = tid + l * 256;
            int m4 = t % (M / 4);
            int kr = t / (M / 4);
            float4 v = *reinterpret_cast<const float4*>(&B[(size_t)(k0 + kr) * M + m4 * 4]);
            *reinterpret_cast<float4*>(&Bs[kr][m4 * 4]) = v;
        }
        __syncthreads();

        #pragma unroll
        for (int kk = 0; kk < BK; ++kk) {
            float bv[TN];
            #pragma unroll
            for (int j = 0; j < TN; ++j) bv[j] = Bs[kk][ct * TN + j];
            #pragma unroll
            for (int i = 0; i < TM; ++i) {
                float av = As[kk][rt * TM + i];
                #pragma unroll
                for (int j = 0; j < TN; ++j)
                    acc[i][j] = fmaf(av, bv[j], acc[i][j]);
            }
        }
        __syncthreads();
    }

    #pragma unroll
    for (int i = 0; i < TM; ++i) {
        int gr = row0 + rt * TM + i;
        if (gr < N) {
            float4 v = make_float4(acc[i][0], acc[i][1], acc[i][2], acc[i][3]);
            *reinterpret_cast<float4*>(&C[(size_t)gr * M + ct * TN]) = v;
        }
    }
}

// ---------------- CSR gather-reduce + fused transform ----------------
// one wave (64 lanes) per dst node; F=128: float2/lane, F=64: float/lane
// mode 0: h = val ; 1: h += val ; 2: h = (h + val)/R (+relu)
template<int F>
__global__ __launch_bounds__(256) void gather_kernel(
    const float* __restrict__ Y, const float* __restrict__ s_out,
    const float* __restrict__ s_in, const float* __restrict__ b,
    const int* __restrict__ row_ptr, const int* __restrict__ col,
    float* __restrict__ h, int mode, int relu)
{
    const int wid  = threadIdx.x >> 6;
    const int lane = threadIdx.x & 63;
    const int n    = blockIdx.x * 4 + wid;
    if (n >= NN) return;
    const int beg = row_ptr[n];
    const int end = row_ptr[n + 1];

    if constexpr (F == 128) {
        const float2* Yp = reinterpret_cast<const float2*>(Y);
        float2 acc = make_float2(0.f, 0.f);
        for (int e = beg; e < end; ++e) {
            int s = col[e];
            float sc = s_out[s];
            float2 v = Yp[(size_t)s * 64 + lane];
            acc.x = fmaf(sc, v.x, acc.x);
            acc.y = fmaf(sc, v.y, acc.y);
        }
        float si = s_in[n];
        float2 bb = reinterpret_cast<const float2*>(b)[lane];
        float2 o;
        o.x = fmaf(acc.x, si, bb.x);
        o.y = fmaf(acc.y, si, bb.y);
        float2* hp = reinterpret_cast<float2*>(h) + (size_t)n * 64 + lane;
        if (mode >= 1) {
            float2 p = *hp;
            o.x += p.x; o.y += p.y;
        }
        if (mode == 2) {
            const float inv = 1.0f / (float)RR;
            o.x *= inv; o.y *= inv;
            if (relu) { o.x = fmaxf(o.x, 0.f); o.y = fmaxf(o.y, 0.f); }
        }
        *hp = o;
    } else {
        float acc = 0.f;
        for (int e = beg; e < end; ++e) {
            int s = col[e];
            float sc = s_out[s];
            acc = fmaf(sc, Y[(size_t)s * F + lane], acc);
        }
        float o = fmaf(acc, s_in[n], b[lane]);
        float* hp = h + (size_t)n * F + lane;
        if (mode >= 1) o += *hp;
        if (mode == 2) {
            o *= 1.0f / (float)RR;
            if (relu) o = fmaxf(o, 0.f);
        }
        *hp = o;
    }
}

// ---------------- edge dot-product scores ----------------
__global__ __launch_bounds__(256) void score_kernel(
    const float* __restrict__ h, const int* __restrict__ src0,
    const int* __restrict__ dst0, const int* __restrict__ nsrc,
    const int* __restrict__ ndst, float* __restrict__ out)
{
    int idx = blockIdx.x * 256 + threadIdx.x;  // grid exact: 2*E*16
    int e = idx >> 4;
    int l = idx & 15;
    int u, v;
    if (e < EE) { u = src0[e]; v = dst0[e]; }
    else        { u = nsrc[e - EE]; v = ndst[e - EE]; }
    float4 a  = *reinterpret_cast<const float4*>(&h[(size_t)u * FOUT + l * 4]);
    float4 bb = *reinterpret_cast<const float4*>(&h[(size_t)v * FOUT + l * 4]);
    float p = a.x * bb.x + a.y * bb.y + a.z * bb.z + a.w * bb.w;
    p += __shfl_xor(p, 8, 16);
    p += __shfl_xor(p, 4, 16);
    p += __shfl_xor(p, 2, 16);
    p += __shfl_xor(p, 1, 16);
    if (l == 0) out[e] = p;
}

// ---------------- launch ----------------
extern "C" void kernel_launch(void* const* d_in, const int* in_sizes, int n_in,
                              void* d_out, int out_size, void* d_ws, size_t ws_size,
                              hipStream_t stream)
{
    const float* feature = (const float*)d_in[0];
    const float* W1      = (const float*)d_in[1];
    const float* b1      = (const float*)d_in[2];
    const float* W2      = (const float*)d_in[3];
    const float* b2      = (const float*)d_in[4];
    const int*   src     = (const int*)d_in[5];
    const int*   dst     = (const int*)d_in[6];
    const int*   nsrc    = (const int*)d_in[7];
    const int*   ndst    = (const int*)d_in[8];
    float* out = (float*)d_out;

    // workspace layout (~141 MB)
    char* p = (char*)d_ws;
    float* s_out   = (float*)p; p += sizeof(float) * RR * NN;
    float* s_in    = (float*)p; p += sizeof(float) * RR * NN;
    float* h1      = (float*)p; p += sizeof(float) * (size_t)NN * FHID;
    float* h2      = (float*)p; p += sizeof(float) * (size_t)NN * FOUT;
    float* Y       = (float*)p; p += sizeof(float) * (size_t)NN * FHID;
    int*   deg_out = (int*)p;   p += sizeof(int) * RR * NN;
    int*   deg_in  = (int*)p;   p += sizeof(int) * RR * NN;   // contiguous w/ deg_out
    int*   row_ptr = (int*)p;   p += sizeof(int) * RR * (NN + 1);
    int*   fill    = (int*)p;   p += sizeof(int) * RR * NN;
    int*   col     = (int*)p;   p += sizeof(int) * (size_t)RR * EE;

    const int edge_grid = (RR * EE + 255) / 256;

    // ---- CSR build + degree scales (shared by both layers) ----
    hipMemsetAsync(deg_out, 0, sizeof(int) * 2 * RR * NN, stream);  // deg_out+deg_in
    hipMemsetAsync(fill,    0, sizeof(int) * RR * NN, stream);
    count_deg_kernel<<<edge_grid, 256, 0, stream>>>(src, dst, deg_out, deg_in);
    finalize_deg_kernel<<<(RR * NN + 255) / 256, 256, 0, stream>>>(deg_out, deg_in, s_out, s_in);
    scan_kernel<<<RR, 1024, 0, stream>>>(deg_in, row_ptr);
    fill_kernel<<<edge_grid, 256, 0, stream>>>(src, dst, row_ptr, fill, col);

    const int gemm_grid = (NN + 63) / 64;
    const int node_grid = (NN + 3) / 4;   // 4 waves/block, 1 node/wave

    // ---- layer 1: h1 = relu(mean_r(gather(feature@W1_r) * s_in + b1_r)) ----
    for (int r = 0; r < RR; ++r) {
        gemm_kernel<FIN, FHID><<<gemm_grid, 256, 0, stream>>>(
            feature, W1 + (size_t)r * FIN * FHID, Y, NN);
        int mode = (r == 0) ? 0 : ((r == RR - 1) ? 2 : 1);
        gather_kernel<FHID><<<node_grid, 256, 0, stream>>>(
            Y, s_out + (size_t)r * NN, s_in + (size_t)r * NN, b1 + (size_t)r * FHID,
            row_ptr + (size_t)r * (NN + 1), col + (size_t)r * EE, h1, mode, 1);
    }

    // ---- layer 2: h2 = mean_r(gather(h1@W2_r) * s_in + b2_r) ----
    for (int r = 0; r < RR; ++r) {
        gemm_kernel<FHID, FOUT><<<gemm_grid, 256, 0, stream>>>(
            h1, W2 + (size_t)r * FHID * FOUT, Y, NN);
        int mode = (r == 0) ? 0 : ((r == RR - 1) ? 2 : 1);
        gather_kernel<FOUT><<<node_grid, 256, 0, stream>>>(
            Y, s_out + (size_t)r * NN, s_in + (size_t)r * NN, b2 + (size_t)r * FOUT,
            row_ptr + (size_t)r * (NN + 1), col + (size_t)r * EE, h2, mode, 0);
    }

    // ---- scores ----
    score_kernel<<<(2 * EE * 16) / 256, 256, 0, stream>>>(h2, src, dst, nsrc, ndst, out);
}

// Round 3
// 1095.029 us; speedup vs baseline: 4.1362x; 1.1204x over previous
//
#include <hip/hip_runtime.h>

// ---- problem constants (match reference) ----
namespace {
constexpr int NN   = 100000;  // nodes
constexpr int RR   = 3;       // relations
constexpr int EE   = 500000;  // edges per relation
constexpr int FIN  = 256;
constexpr int FHID = 128;
constexpr int FOUT = 64;
constexpr int SCAN_TILE = 4096;                       // elems per scan block
constexpr int NB = (NN + SCAN_TILE - 1) / SCAN_TILE;  // 25 blocks per relation
}

// ---------------- degree count (int atomics, L2-resident) ----------------
__global__ __launch_bounds__(256) void count_deg_kernel(
    const int* __restrict__ src, const int* __restrict__ dst,
    int* __restrict__ deg_out, int* __restrict__ deg_in)
{
    int idx = blockIdx.x * 256 + threadIdx.x;
    if (idx >= RR * EE) return;
    int r = idx / EE;
    atomicAdd(&deg_out[(size_t)r * NN + src[idx]], 1);
    atomicAdd(&deg_in [(size_t)r * NN + dst[idx]], 1);
}

__global__ __launch_bounds__(256) void finalize_deg_kernel(
    const int* __restrict__ deg_out, const int* __restrict__ deg_in,
    float* __restrict__ s_out, float* __restrict__ s_in)
{
    int idx = blockIdx.x * 256 + threadIdx.x;
    if (idx >= RR * NN) return;
    s_out[idx] = rsqrtf((float)max(deg_out[idx], 1));
    s_in [idx] = rsqrtf((float)max(deg_in [idx], 1));
}

// ---------------- 3-phase scan: deg_in -> row_ptr (exclusive, per relation) ----
__global__ __launch_bounds__(1024) void scan_reduce_kernel(
    const int* __restrict__ deg_in, int* __restrict__ bsum)
{
    const int r = blockIdx.x / NB;
    const int b = blockIdx.x % NB;
    const int t = threadIdx.x;
    const int* deg = deg_in + (size_t)r * NN;
    int n0 = b * SCAN_TILE + t * 4;
    int s = 0;
    if (n0 + 3 < NN) {
        int4 q = *reinterpret_cast<const int4*>(&deg[n0]);
        s = q.x + q.y + q.z + q.w;
    } else {
        for (int i = 0; i < 4; ++i) if (n0 + i < NN) s += deg[n0 + i];
    }
    __shared__ int sh[1024];
    sh[t] = s;
    __syncthreads();
    for (int off = 512; off > 0; off >>= 1) {
        if (t < off) sh[t] += sh[t + off];
        __syncthreads();
    }
    if (t == 0) bsum[blockIdx.x] = sh[0];
}

__global__ void scan_spine_kernel(int* __restrict__ bsum)
{
    // grid = RR blocks; serial exclusive scan of NB=25 values (trivial)
    if (threadIdx.x != 0) return;
    int r = blockIdx.x;
    int run = 0;
    for (int i = 0; i < NB; ++i) {
        int v = bsum[r * NB + i];
        bsum[r * NB + i] = run;
        run += v;
    }
}

__global__ __launch_bounds__(1024) void scan_final_kernel(
    const int* __restrict__ deg_in, const int* __restrict__ bsum,
    int* __restrict__ row_ptr)
{
    const int r = blockIdx.x / NB;
    const int b = blockIdx.x % NB;
    const int t = threadIdx.x;
    const int* deg = deg_in + (size_t)r * NN;
    int* rp = row_ptr + (size_t)r * (NN + 1);
    int n0 = b * SCAN_TILE + t * 4;
    int v[4] = {0, 0, 0, 0};
    if (n0 + 3 < NN) {
        int4 q = *reinterpret_cast<const int4*>(&deg[n0]);
        v[0] = q.x; v[1] = q.y; v[2] = q.z; v[3] = q.w;
    } else {
        for (int i = 0; i < 4; ++i) if (n0 + i < NN) v[i] = deg[n0 + i];
    }
    int s = v[0] + v[1] + v[2] + v[3];
    __shared__ int sh[1024];
    sh[t] = s;
    __syncthreads();
    for (int off = 1; off < 1024; off <<= 1) {
        int x = (t >= off) ? sh[t - off] : 0;
        __syncthreads();
        if (t >= off) sh[t] += x;
        __syncthreads();
    }
    int off = bsum[blockIdx.x] + sh[t] - s;   // exclusive prefix for n0
    for (int i = 0; i < 4; ++i) {
        if (n0 + i < NN) { rp[n0 + i] = off; off += v[i]; }
    }
    if (b == NB - 1 && t == 0) rp[NN] = EE;
}

// ---------------- CSR fill: col[] = src ids grouped by dst ----------------
__global__ __launch_bounds__(256) void fill_kernel(
    const int* __restrict__ src, const int* __restrict__ dst,
    const int* __restrict__ row_ptr, int* __restrict__ fill,
    int* __restrict__ col)
{
    int idx = blockIdx.x * 256 + threadIdx.x;
    if (idx >= RR * EE) return;
    int r = idx / EE;
    int d = dst[idx];
    int pos = row_ptr[(size_t)r * (NN + 1) + d] + atomicAdd(&fill[(size_t)r * NN + d], 1);
    col[(size_t)r * EE + pos] = src[idx];
}

// ---------------- GEMM: C[N,M] = A[N,K] @ B[K,M] (f32, vector ALU) ----------------
// 128 x M block tile, 256 threads, per-thread 8 x (M==128?8:4) micro-tile
template<int K, int M>
__global__ __launch_bounds__(256) void gemm_kernel(
    const float* __restrict__ A, const float* __restrict__ B,
    float* __restrict__ C, int N)
{
    constexpr int BM = 128;
    constexpr int BK = 32;
    constexpr int BN = M;                 // 128 or 64
    constexpr int TN = (M >= 128) ? 8 : 4;
    constexpr int CT = BN / TN;           // 16
    constexpr int RT = 256 / CT;          // 16
    constexpr int TM = BM / RT;           // 8
    constexpr int AS_STRIDE = BM + 4;     // 132: rows 16B-aligned, staggered banks

    __shared__ float As[BK][AS_STRIDE];   // transposed A tile: As[k][row]
    __shared__ float Bs[BK][BN];

    const int tid  = threadIdx.x;
    const int row0 = blockIdx.x * BM;
    const int ct   = tid % CT;
    const int rt   = tid / CT;

    float acc[TM][TN];
    #pragma unroll
    for (int i = 0; i < TM; ++i)
        #pragma unroll
        for (int j = 0; j < TN; ++j) acc[i][j] = 0.0f;

    for (int k0 = 0; k0 < K; k0 += BK) {
        // stage A tile (128 rows x 32 k), stored transposed
        #pragma unroll
        for (int l = 0; l < (BM * BK) / (4 * 256); ++l) {   // 4 iters
            int t  = tid + l * 256;        // 0..1023
            int r  = t >> 3;               // row in tile (8 float4 per row)
            int kv = t & 7;
            int gr = row0 + r;
            float4 v = make_float4(0.f, 0.f, 0.f, 0.f);
            if (gr < N)
                v = *reinterpret_cast<const float4*>(&A[(size_t)gr * K + k0 + kv * 4]);
            As[kv * 4 + 0][r] = v.x;
            As[kv * 4 + 1][r] = v.y;
            As[kv * 4 + 2][r] = v.z;
            As[kv * 4 + 3][r] = v.w;
        }
        // stage B tile (32 k x BN)
        #pragma unroll
        for (int l = 0; l < (BK * BN) / (4 * 256); ++l) {   // 4 (BN=128) / 2 (BN=64)
            int t  = tid + l * 256;
            int m4 = t % (BN / 4);
            int kr = t / (BN / 4);
            float4 v = *reinterpret_cast<const float4*>(&B[(size_t)(k0 + kr) * M + m4 * 4]);
            *reinterpret_cast<float4*>(&Bs[kr][m4 * 4]) = v;
        }
        __syncthreads();

        #pragma unroll
        for (int kk = 0; kk < BK; ++kk) {
            float bv[TN];
            #pragma unroll
            for (int j = 0; j < TN; ++j) bv[j] = Bs[kk][ct * TN + j];
            float av[TM];
            #pragma unroll
            for (int i = 0; i < TM; ++i) av[i] = As[kk][rt * TM + i];
            #pragma unroll
            for (int i = 0; i < TM; ++i)
                #pragma unroll
                for (int j = 0; j < TN; ++j)
                    acc[i][j] = fmaf(av[i], bv[j], acc[i][j]);
        }
        __syncthreads();
    }

    #pragma unroll
    for (int i = 0; i < TM; ++i) {
        int gr = row0 + rt * TM + i;
        if (gr < N) {
            #pragma unroll
            for (int j4 = 0; j4 < TN / 4; ++j4) {
                float4 v = make_float4(acc[i][j4 * 4 + 0], acc[i][j4 * 4 + 1],
                                       acc[i][j4 * 4 + 2], acc[i][j4 * 4 + 3]);
                *reinterpret_cast<float4*>(&C[(size_t)gr * M + ct * TN + j4 * 4]) = v;
            }
        }
    }
}

// ---------------- CSR gather-reduce + fused transform ----------------
// one wave (64 lanes) per dst node; F=128: float2/lane, F=64: float/lane
// mode 0: h = val ; 1: h += val ; 2: h = (h + val)/R (+relu)
template<int F>
__global__ __launch_bounds__(256) void gather_kernel(
    const float* __restrict__ Y, const float* __restrict__ s_out,
    const float* __restrict__ s_in, const float* __restrict__ b,
    const int* __restrict__ row_ptr, const int* __restrict__ col,
    float* __restrict__ h, int mode, int relu)
{
    const int wid  = threadIdx.x >> 6;
    const int lane = threadIdx.x & 63;
    const int n    = blockIdx.x * 4 + wid;
    if (n >= NN) return;
    const int beg = row_ptr[n];
    const int end = row_ptr[n + 1];

    if constexpr (F == 128) {
        const float2* Yp = reinterpret_cast<const float2*>(Y);
        float2 acc = make_float2(0.f, 0.f);
        for (int e = beg; e < end; ++e) {
            int s = col[e];
            float sc = s_out[s];
            float2 v = Yp[(size_t)s * 64 + lane];
            acc.x = fmaf(sc, v.x, acc.x);
            acc.y = fmaf(sc, v.y, acc.y);
        }
        float si = s_in[n];
        float2 bb = reinterpret_cast<const float2*>(b)[lane];
        float2 o;
        o.x = fmaf(acc.x, si, bb.x);
        o.y = fmaf(acc.y, si, bb.y);
        float2* hp = reinterpret_cast<float2*>(h) + (size_t)n * 64 + lane;
        if (mode >= 1) {
            float2 p = *hp;
            o.x += p.x; o.y += p.y;
        }
        if (mode == 2) {
            const float inv = 1.0f / (float)RR;
            o.x *= inv; o.y *= inv;
            if (relu) { o.x = fmaxf(o.x, 0.f); o.y = fmaxf(o.y, 0.f); }
        }
        *hp = o;
    } else {
        float acc = 0.f;
        for (int e = beg; e < end; ++e) {
            int s = col[e];
            float sc = s_out[s];
            acc = fmaf(sc, Y[(size_t)s * F + lane], acc);
        }
        float o = fmaf(acc, s_in[n], b[lane]);
        float* hp = h + (size_t)n * F + lane;
        if (mode >= 1) o += *hp;
        if (mode == 2) {
            o *= 1.0f / (float)RR;
            if (relu) o = fmaxf(o, 0.f);
        }
        *hp = o;
    }
}

// ---------------- edge dot-product scores ----------------
__global__ __launch_bounds__(256) void score_kernel(
    const float* __restrict__ h, const int* __restrict__ src0,
    const int* __restrict__ dst0, const int* __restrict__ nsrc,
    const int* __restrict__ ndst, float* __restrict__ out)
{
    int idx = blockIdx.x * 256 + threadIdx.x;  // grid exact: 2*E*16
    int e = idx >> 4;
    int l = idx & 15;
    int u, v;
    if (e < EE) { u = src0[e]; v = dst0[e]; }
    else        { u = nsrc[e - EE]; v = ndst[e - EE]; }
    float4 a  = *reinterpret_cast<const float4*>(&h[(size_t)u * FOUT + l * 4]);
    float4 bb = *reinterpret_cast<const float4*>(&h[(size_t)v * FOUT + l * 4]);
    float p = a.x * bb.x + a.y * bb.y + a.z * bb.z + a.w * bb.w;
    p += __shfl_xor(p, 8, 16);
    p += __shfl_xor(p, 4, 16);
    p += __shfl_xor(p, 2, 16);
    p += __shfl_xor(p, 1, 16);
    if (l == 0) out[e] = p;
}

// ---------------- launch ----------------
extern "C" void kernel_launch(void* const* d_in, const int* in_sizes, int n_in,
                              void* d_out, int out_size, void* d_ws, size_t ws_size,
                              hipStream_t stream)
{
    const float* feature = (const float*)d_in[0];
    const float* W1      = (const float*)d_in[1];
    const float* b1      = (const float*)d_in[2];
    const float* W2      = (const float*)d_in[3];
    const float* b2      = (const float*)d_in[4];
    const int*   src     = (const int*)d_in[5];
    const int*   dst     = (const int*)d_in[6];
    const int*   nsrc    = (const int*)d_in[7];
    const int*   ndst    = (const int*)d_in[8];
    float* out = (float*)d_out;

    // workspace layout (~141 MB)
    char* p = (char*)d_ws;
    float* s_out   = (float*)p; p += sizeof(float) * RR * NN;
    float* s_in    = (float*)p; p += sizeof(float) * RR * NN;
    float* h1      = (float*)p; p += sizeof(float) * (size_t)NN * FHID;
    float* h2      = (float*)p; p += sizeof(float) * (size_t)NN * FOUT;
    float* Y       = (float*)p; p += sizeof(float) * (size_t)NN * FHID;
    int*   deg_out = (int*)p;   p += sizeof(int) * RR * NN;
    int*   deg_in  = (int*)p;   p += sizeof(int) * RR * NN;   // contiguous w/ deg_out
    int*   row_ptr = (int*)p;   p += sizeof(int) * RR * (NN + 1);
    int*   fill    = (int*)p;   p += sizeof(int) * RR * NN;
    int*   col     = (int*)p;   p += sizeof(int) * (size_t)RR * EE;
    int*   bsum    = (int*)p;   p += sizeof(int) * RR * NB;

    const int edge_grid = (RR * EE + 255) / 256;

    // ---- CSR build + degree scales (shared by both layers) ----
    hipMemsetAsync(deg_out, 0, sizeof(int) * 2 * RR * NN, stream);  // deg_out+deg_in
    hipMemsetAsync(fill,    0, sizeof(int) * RR * NN, stream);
    count_deg_kernel<<<edge_grid, 256, 0, stream>>>(src, dst, deg_out, deg_in);
    finalize_deg_kernel<<<(RR * NN + 255) / 256, 256, 0, stream>>>(deg_out, deg_in, s_out, s_in);
    scan_reduce_kernel<<<RR * NB, 1024, 0, stream>>>(deg_in, bsum);
    scan_spine_kernel<<<RR, 64, 0, stream>>>(bsum);
    scan_final_kernel<<<RR * NB, 1024, 0, stream>>>(deg_in, bsum, row_ptr);
    fill_kernel<<<edge_grid, 256, 0, stream>>>(src, dst, row_ptr, fill, col);

    const int gemm_grid = (NN + 127) / 128;
    const int node_grid = (NN + 3) / 4;   // 4 waves/block, 1 node/wave

    // ---- layer 1: h1 = relu(mean_r(gather(feature@W1_r) * s_in + b1_r)) ----
    for (int r = 0; r < RR; ++r) {
        gemm_kernel<FIN, FHID><<<gemm_grid, 256, 0, stream>>>(
            feature, W1 + (size_t)r * FIN * FHID, Y, NN);
        int mode = (r == 0) ? 0 : ((r == RR - 1) ? 2 : 1);
        gather_kernel<FHID><<<node_grid, 256, 0, stream>>>(
            Y, s_out + (size_t)r * NN, s_in + (size_t)r * NN, b1 + (size_t)r * FHID,
            row_ptr + (size_t)r * (NN + 1), col + (size_t)r * EE, h1, mode, 1);
    }

    // ---- layer 2: h2 = mean_r(gather(h1@W2_r) * s_in + b2_r) ----
    for (int r = 0; r < RR; ++r) {
        gemm_kernel<FHID, FOUT><<<gemm_grid, 256, 0, stream>>>(
            h1, W2 + (size_t)r * FHID * FOUT, Y, NN);
        int mode = (r == 0) ? 0 : ((r == RR - 1) ? 2 : 1);
        gather_kernel<FOUT><<<node_grid, 256, 0, stream>>>(
            Y, s_out + (size_t)r * NN, s_in + (size_t)r * NN, b2 + (size_t)r * FOUT,
            row_ptr + (size_t)r * (NN + 1), col + (size_t)r * EE, h2, mode, 0);
    }

    // ---- scores ----
    score_kernel<<<(2 * EE * 16) / 256, 256, 0, stream>>>(h2, src, dst, nsrc, ndst, out);
}

// Round 4
// 817.612 us; speedup vs baseline: 5.5396x; 1.3393x over previous
//
#include <hip/hip_runtime.h>

// ---- problem constants (match reference) ----
namespace {
constexpr int NN   = 100000;  // nodes
constexpr int RR   = 3;       // relations
constexpr int EE   = 500000;  // edges per relation
constexpr int FIN  = 256;
constexpr int FHID = 128;
constexpr int FOUT = 64;
constexpr int SCAN_TILE = 4096;                       // elems per scan block
constexpr int NB = (NN + SCAN_TILE - 1) / SCAN_TILE;  // 25 blocks per relation
}

typedef float f32x4  __attribute__((ext_vector_type(4)));
typedef short bf16x8 __attribute__((ext_vector_type(8)));

__device__ inline unsigned pack2_bf16(float a, float b) {
    unsigned ua = __float_as_uint(a), ub = __float_as_uint(b);
    ua = (ua + 0x7FFFu + ((ua >> 16) & 1u)) >> 16;   // RNE
    ub = (ub + 0x7FFFu + ((ub >> 16) & 1u)) >> 16;
    return ua | (ub << 16);
}

// ---------------- degree count (int atomics, L2-resident) ----------------
__global__ __launch_bounds__(256) void count_deg_kernel(
    const int* __restrict__ src, const int* __restrict__ dst,
    int* __restrict__ deg_out, int* __restrict__ deg_in)
{
    int idx = blockIdx.x * 256 + threadIdx.x;
    if (idx >= RR * EE) return;
    int r = idx / EE;
    atomicAdd(&deg_out[(size_t)r * NN + src[idx]], 1);
    atomicAdd(&deg_in [(size_t)r * NN + dst[idx]], 1);
}

__global__ __launch_bounds__(256) void finalize_deg_kernel(
    const int* __restrict__ deg_out, const int* __restrict__ deg_in,
    float* __restrict__ s_out, float* __restrict__ s_in)
{
    int idx = blockIdx.x * 256 + threadIdx.x;
    if (idx >= RR * NN) return;
    s_out[idx] = rsqrtf((float)max(deg_out[idx], 1));
    s_in [idx] = rsqrtf((float)max(deg_in [idx], 1));
}

// ---------------- 3-phase scan: deg_in -> row_ptr (exclusive, per relation) ----
__global__ __launch_bounds__(1024) void scan_reduce_kernel(
    const int* __restrict__ deg_in, int* __restrict__ bsum)
{
    const int r = blockIdx.x / NB;
    const int b = blockIdx.x % NB;
    const int t = threadIdx.x;
    const int* deg = deg_in + (size_t)r * NN;
    int n0 = b * SCAN_TILE + t * 4;
    int s = 0;
    if (n0 + 3 < NN) {
        int4 q = *reinterpret_cast<const int4*>(&deg[n0]);
        s = q.x + q.y + q.z + q.w;
    } else {
        for (int i = 0; i < 4; ++i) if (n0 + i < NN) s += deg[n0 + i];
    }
    __shared__ int sh[1024];
    sh[t] = s;
    __syncthreads();
    for (int off = 512; off > 0; off >>= 1) {
        if (t < off) sh[t] += sh[t + off];
        __syncthreads();
    }
    if (t == 0) bsum[blockIdx.x] = sh[0];
}

__global__ void scan_spine_kernel(int* __restrict__ bsum)
{
    if (threadIdx.x != 0) return;
    int r = blockIdx.x;
    int run = 0;
    for (int i = 0; i < NB; ++i) {
        int v = bsum[r * NB + i];
        bsum[r * NB + i] = run;
        run += v;
    }
}

__global__ __launch_bounds__(1024) void scan_final_kernel(
    const int* __restrict__ deg_in, const int* __restrict__ bsum,
    int* __restrict__ row_ptr)
{
    const int r = blockIdx.x / NB;
    const int b = blockIdx.x % NB;
    const int t = threadIdx.x;
    const int* deg = deg_in + (size_t)r * NN;
    int* rp = row_ptr + (size_t)r * (NN + 1);
    int n0 = b * SCAN_TILE + t * 4;
    int v[4] = {0, 0, 0, 0};
    if (n0 + 3 < NN) {
        int4 q = *reinterpret_cast<const int4*>(&deg[n0]);
        v[0] = q.x; v[1] = q.y; v[2] = q.z; v[3] = q.w;
    } else {
        for (int i = 0; i < 4; ++i) if (n0 + i < NN) v[i] = deg[n0 + i];
    }
    int s = v[0] + v[1] + v[2] + v[3];
    __shared__ int sh[1024];
    sh[t] = s;
    __syncthreads();
    for (int off = 1; off < 1024; off <<= 1) {
        int x = (t >= off) ? sh[t - off] : 0;
        __syncthreads();
        if (t >= off) sh[t] += x;
        __syncthreads();
    }
    int off = bsum[blockIdx.x] + sh[t] - s;
    for (int i = 0; i < 4; ++i) {
        if (n0 + i < NN) { rp[n0 + i] = off; off += v[i]; }
    }
    if (b == NB - 1 && t == 0) rp[NN] = EE;
}

// ---------------- CSR fill: col[] = src ids grouped by dst ----------------
__global__ __launch_bounds__(256) void fill_kernel(
    const int* __restrict__ src, const int* __restrict__ dst,
    const int* __restrict__ row_ptr, int* __restrict__ fill,
    int* __restrict__ col)
{
    int idx = blockIdx.x * 256 + threadIdx.x;
    if (idx >= RR * EE) return;
    int r = idx / EE;
    int d = dst[idx];
    int pos = row_ptr[(size_t)r * (NN + 1) + d] + atomicAdd(&fill[(size_t)r * NN + d], 1);
    col[(size_t)r * EE + pos] = src[idx];
}

// ---------------- weight transpose + bf16 convert: Wt[r][m][k] = bf16(W[r][k][m]) ----
__global__ __launch_bounds__(256) void convw_kernel(
    const float* __restrict__ W, unsigned short* __restrict__ Wt, int K, int M, int total)
{
    int idx = blockIdx.x * 256 + threadIdx.x;
    if (idx >= total) return;
    int r = idx / (K * M);
    int rem = idx - r * K * M;
    int k = rem / M;
    int m = rem - k * M;
    unsigned u = __float_as_uint(W[idx]);
    u = (u + 0x7FFFu + ((u >> 16) & 1u)) >> 16;
    Wt[((size_t)r * M + m) * K + k] = (unsigned short)u;
}

// ---------------- bf16 MFMA GEMM: C[N,BN] = A[N,K](f32->bf16) @ Wt[BN,K]^T ----------
// BM=128, BK=32, 4 waves in 2x2; per-wave 64 x BN/2 output; 16x16x32 MFMA.
template<int K, int BN>
__global__ __launch_bounds__(256) void gemm_bf16_kernel(
    const float* __restrict__ A, const unsigned short* __restrict__ Wt,
    float* __restrict__ C, int N)
{
    constexpr int BM  = 128;
    constexpr int BK  = 32;
    constexpr int LDT = 56;            // bf16 elems per LDS row: 112 B, 16B-aligned, 2-way banks
    constexpr int MF  = 4;             // 4 m-fragments (64 rows per wave)
    constexpr int NF  = BN / 32;       // n-fragments per wave (half of BN across 2 waves)

    __shared__ unsigned short As[BM * LDT];
    __shared__ unsigned short Bs[BN * LDT];

    const int tid  = threadIdx.x;
    const int wave = tid >> 6;
    const int lane = tid & 63;
    const int wr   = wave >> 1;        // 0..1
    const int wc   = wave & 1;         // 0..1
    const int row0 = blockIdx.x * BM;
    const int l15  = lane & 15;
    const int lq   = lane >> 4;        // 0..3

    f32x4 acc[MF][NF];
    #pragma unroll
    for (int mi = 0; mi < MF; ++mi)
        #pragma unroll
        for (int ni = 0; ni < NF; ++ni)
            #pragma unroll
            for (int q = 0; q < 4; ++q) acc[mi][ni][q] = 0.0f;

    for (int k0 = 0; k0 < K; k0 += BK) {
        // ---- stage A tile: 128 rows x 32 k, f32 -> bf16 RNE ----
        #pragma unroll
        for (int l = 0; l < (BM * 8) / 256; ++l) {     // 4 iters
            int c  = tid + l * 256;                    // 0..1023
            int r  = c >> 3;                           // row in tile
            int kc = c & 7;                            // float4 chunk in k
            float4 v = make_float4(0.f, 0.f, 0.f, 0.f);
            if (row0 + r < N)
                v = *reinterpret_cast<const float4*>(&A[(size_t)(row0 + r) * K + k0 + kc * 4]);
            uint2 pk;
            pk.x = pack2_bf16(v.x, v.y);
            pk.y = pack2_bf16(v.z, v.w);
            *reinterpret_cast<uint2*>(&As[r * LDT + kc * 4]) = pk;
        }
        // ---- stage B tile: BN rows (n) x 32 k from Wt (already bf16, row-major [n][k]) ----
        #pragma unroll
        for (int l = 0; l < (BN * 4) / 256; ++l) {     // 2 (BN=128) / 1 (BN=64)
            int c  = tid + l * 256;
            int r  = c >> 2;                           // n row
            int kc = c & 3;                            // 8-bf16 chunk in k
            *reinterpret_cast<uint4*>(&Bs[r * LDT + kc * 8]) =
                *reinterpret_cast<const uint4*>(&Wt[(size_t)r * K + k0 + kc * 8]);
        }
        __syncthreads();

        bf16x8 af[MF], bfg[NF];
        #pragma unroll
        for (int mi = 0; mi < MF; ++mi)
            af[mi] = *reinterpret_cast<const bf16x8*>(
                &As[(wr * 64 + mi * 16 + l15) * LDT + lq * 8]);
        #pragma unroll
        for (int ni = 0; ni < NF; ++ni)
            bfg[ni] = *reinterpret_cast<const bf16x8*>(
                &Bs[(wc * (BN / 2) + ni * 16 + l15) * LDT + lq * 8]);
        #pragma unroll
        for (int mi = 0; mi < MF; ++mi)
            #pragma unroll
            for (int ni = 0; ni < NF; ++ni)
                acc[mi][ni] = __builtin_amdgcn_mfma_f32_16x16x32_bf16(
                    af[mi], bfg[ni], acc[mi][ni], 0, 0, 0);
        __syncthreads();
    }

    // ---- write C (f32): D layout col=lane&15, row=(lane>>4)*4+reg ----
    #pragma unroll
    for (int mi = 0; mi < MF; ++mi) {
        int rbase = row0 + wr * 64 + mi * 16 + lq * 4;
        #pragma unroll
        for (int ni = 0; ni < NF; ++ni) {
            int cc = wc * (BN / 2) + ni * 16 + l15;
            #pragma unroll
            for (int q = 0; q < 4; ++q) {
                int rr = rbase + q;
                if (rr < N) C[(size_t)rr * BN + cc] = acc[mi][ni][q];
            }
        }
    }
}

// ---------------- CSR gather-reduce + fused transform ----------------
// one wave (64 lanes) per dst node; F=128: float2/lane, F=64: float/lane
// mode 0: h = val ; 1: h += val ; 2: h = (h + val)/R (+relu)
template<int F>
__global__ __launch_bounds__(256) void gather_kernel(
    const float* __restrict__ Y, const float* __restrict__ s_out,
    const float* __restrict__ s_in, const float* __restrict__ b,
    const int* __restrict__ row_ptr, const int* __restrict__ col,
    float* __restrict__ h, int mode, int relu)
{
    const int wid  = threadIdx.x >> 6;
    const int lane = threadIdx.x & 63;
    const int n    = blockIdx.x * 4 + wid;
    if (n >= NN) return;
    const int beg = row_ptr[n];
    const int end = row_ptr[n + 1];

    if constexpr (F == 128) {
        const float2* Yp = reinterpret_cast<const float2*>(Y);
        float2 acc = make_float2(0.f, 0.f);
        for (int e = beg; e < end; ++e) {
            int s = col[e];
            float sc = s_out[s];
            float2 v = Yp[(size_t)s * 64 + lane];
            acc.x = fmaf(sc, v.x, acc.x);
            acc.y = fmaf(sc, v.y, acc.y);
        }
        float si = s_in[n];
        float2 bb = reinterpret_cast<const float2*>(b)[lane];
        float2 o;
        o.x = fmaf(acc.x, si, bb.x);
        o.y = fmaf(acc.y, si, bb.y);
        float2* hp = reinterpret_cast<float2*>(h) + (size_t)n * 64 + lane;
        if (mode >= 1) {
            float2 p = *hp;
            o.x += p.x; o.y += p.y;
        }
        if (mode == 2) {
            const float inv = 1.0f / (float)RR;
            o.x *= inv; o.y *= inv;
            if (relu) { o.x = fmaxf(o.x, 0.f); o.y = fmaxf(o.y, 0.f); }
        }
        *hp = o;
    } else {
        float acc = 0.f;
        for (int e = beg; e < end; ++e) {
            int s = col[e];
            float sc = s_out[s];
            acc = fmaf(sc, Y[(size_t)s * F + lane], acc);
        }
        float o = fmaf(acc, s_in[n], b[lane]);
        float* hp = h + (size_t)n * F + lane;
        if (mode >= 1) o += *hp;
        if (mode == 2) {
            o *= 1.0f / (float)RR;
            if (relu) o = fmaxf(o, 0.f);
        }
        *hp = o;
    }
}

// ---------------- edge dot-product scores ----------------
__global__ __launch_bounds__(256) void score_kernel(
    const float* __restrict__ h, const int* __restrict__ src0,
    const int* __restrict__ dst0, const int* __restrict__ nsrc,
    const int* __restrict__ ndst, float* __restrict__ out)
{
    int idx = blockIdx.x * 256 + threadIdx.x;  // grid exact: 2*E*16
    int e = idx >> 4;
    int l = idx & 15;
    int u, v;
    if (e < EE) { u = src0[e]; v = dst0[e]; }
    else        { u = nsrc[e - EE]; v = ndst[e - EE]; }
    float4 a  = *reinterpret_cast<const float4*>(&h[(size_t)u * FOUT + l * 4]);
    float4 bb = *reinterpret_cast<const float4*>(&h[(size_t)v * FOUT + l * 4]);
    float p = a.x * bb.x + a.y * bb.y + a.z * bb.z + a.w * bb.w;
    p += __shfl_xor(p, 8, 16);
    p += __shfl_xor(p, 4, 16);
    p += __shfl_xor(p, 2, 16);
    p += __shfl_xor(p, 1, 16);
    if (l == 0) out[e] = p;
}

// ---------------- launch ----------------
extern "C" void kernel_launch(void* const* d_in, const int* in_sizes, int n_in,
                              void* d_out, int out_size, void* d_ws, size_t ws_size,
                              hipStream_t stream)
{
    const float* feature = (const float*)d_in[0];
    const float* W1      = (const float*)d_in[1];
    const float* b1      = (const float*)d_in[2];
    const float* W2      = (const float*)d_in[3];
    const float* b2      = (const float*)d_in[4];
    const int*   src     = (const int*)d_in[5];
    const int*   dst     = (const int*)d_in[6];
    const int*   nsrc    = (const int*)d_in[7];
    const int*   ndst    = (const int*)d_in[8];
    float* out = (float*)d_out;

    // workspace layout (~142 MB)
    char* p = (char*)d_ws;
    float* s_out   = (float*)p; p += sizeof(float) * RR * NN;
    float* s_in    = (float*)p; p += sizeof(float) * RR * NN;
    float* h1      = (float*)p; p += sizeof(float) * (size_t)NN * FHID;
    float* h2      = (float*)p; p += sizeof(float) * (size_t)NN * FOUT;
    float* Y       = (float*)p; p += sizeof(float) * (size_t)NN * FHID;
    int*   deg_out = (int*)p;   p += sizeof(int) * RR * NN;
    int*   deg_in  = (int*)p;   p += sizeof(int) * RR * NN;   // contiguous w/ deg_out
    int*   row_ptr = (int*)p;   p += sizeof(int) * RR * (NN + 1);
    int*   fill    = (int*)p;   p += sizeof(int) * RR * NN;
    int*   col     = (int*)p;   p += sizeof(int) * (size_t)RR * EE;
    int*   bsum    = (int*)p;   p += sizeof(int) * RR * NB;
    unsigned short* Wt1 = (unsigned short*)p; p += sizeof(unsigned short) * RR * FIN * FHID;
    unsigned short* Wt2 = (unsigned short*)p; p += sizeof(unsigned short) * RR * FHID * FOUT;

    const int edge_grid = (RR * EE + 255) / 256;

    // ---- CSR build + degree scales + weight conversion ----
    hipMemsetAsync(deg_out, 0, sizeof(int) * 2 * RR * NN, stream);
    hipMemsetAsync(fill,    0, sizeof(int) * RR * NN, stream);
    count_deg_kernel<<<edge_grid, 256, 0, stream>>>(src, dst, deg_out, deg_in);
    finalize_deg_kernel<<<(RR * NN + 255) / 256, 256, 0, stream>>>(deg_out, deg_in, s_out, s_in);
    scan_reduce_kernel<<<RR * NB, 1024, 0, stream>>>(deg_in, bsum);
    scan_spine_kernel<<<RR, 64, 0, stream>>>(bsum);
    scan_final_kernel<<<RR * NB, 1024, 0, stream>>>(deg_in, bsum, row_ptr);
    fill_kernel<<<edge_grid, 256, 0, stream>>>(src, dst, row_ptr, fill, col);
    convw_kernel<<<(RR * FIN * FHID + 255) / 256, 256, 0, stream>>>(
        W1, Wt1, FIN, FHID, RR * FIN * FHID);
    convw_kernel<<<(RR * FHID * FOUT + 255) / 256, 256, 0, stream>>>(
        W2, Wt2, FHID, FOUT, RR * FHID * FOUT);

    const int gemm_grid = (NN + 127) / 128;
    const int node_grid = (NN + 3) / 4;   // 4 waves/block, 1 node/wave

    // ---- layer 1: h1 = relu(mean_r(gather(feature@W1_r) * s_in + b1_r)) ----
    for (int r = 0; r < RR; ++r) {
        gemm_bf16_kernel<FIN, FHID><<<gemm_grid, 256, 0, stream>>>(
            feature, Wt1 + (size_t)r * FIN * FHID, Y, NN);
        int mode = (r == 0) ? 0 : ((r == RR - 1) ? 2 : 1);
        gather_kernel<FHID><<<node_grid, 256, 0, stream>>>(
            Y, s_out + (size_t)r * NN, s_in + (size_t)r * NN, b1 + (size_t)r * FHID,
            row_ptr + (size_t)r * (NN + 1), col + (size_t)r * EE, h1, mode, 1);
    }

    // ---- layer 2: h2 = mean_r(gather(h1@W2_r) * s_in + b2_r) ----
    for (int r = 0; r < RR; ++r) {
        gemm_bf16_kernel<FHID, FOUT><<<gemm_grid, 256, 0, stream>>>(
            h1, Wt2 + (size_t)r * FHID * FOUT, Y, NN);
        int mode = (r == 0) ? 0 : ((r == RR - 1) ? 2 : 1);
        gather_kernel<FOUT><<<node_grid, 256, 0, stream>>>(
            Y, s_out + (size_t)r * NN, s_in + (size_t)r * NN, b2 + (size_t)r * FOUT,
            row_ptr + (size_t)r * (NN + 1), col + (size_t)r * EE, h2, mode, 0);
    }

    // ---- scores ----
    score_kernel<<<(2 * EE * 16) / 256, 256, 0, stream>>>(h2, src, dst, nsrc, ndst, out);
}

// Round 6
// 658.839 us; speedup vs baseline: 6.8746x; 1.2410x over previous
//
#include <hip/hip_runtime.h>

// ---- problem constants (match reference) ----
namespace {
constexpr int NN   = 100000;  // nodes
constexpr int RR   = 3;       // relations
constexpr int EE   = 500000;  // edges per relation
constexpr int FIN  = 256;
constexpr int FHID = 128;
constexpr int FOUT = 64;
constexpr int SCAN_TILE = 4096;                       // elems per scan block
constexpr int NB = (NN + SCAN_TILE - 1) / SCAN_TILE;  // 25 blocks per relation
}

typedef float f32x4  __attribute__((ext_vector_type(4)));
typedef short bf16x8 __attribute__((ext_vector_type(8)));

__device__ inline unsigned bf16round(float a) {
    unsigned u = __float_as_uint(a);
    return (u + 0x7FFFu + ((u >> 16) & 1u)) >> 16;   // RNE
}
__device__ inline unsigned pack2_bf16(float a, float b) {
    return bf16round(a) | (bf16round(b) << 16);
}

// ---------------- degree count (int atomics) ----------------
__global__ __launch_bounds__(256) void count_deg_kernel(
    const int* __restrict__ src, const int* __restrict__ dst,
    int* __restrict__ deg_out, int* __restrict__ deg_in)
{
    int idx = blockIdx.x * 256 + threadIdx.x;
    if (idx >= RR * EE) return;
    int r = idx / EE;
    atomicAdd(&deg_out[(size_t)r * NN + src[idx]], 1);
    atomicAdd(&deg_in [(size_t)r * NN + dst[idx]], 1);
}

__global__ __launch_bounds__(256) void finalize_deg_kernel(
    const int* __restrict__ deg_out, const int* __restrict__ deg_in,
    float* __restrict__ s_out, float* __restrict__ s_in)
{
    int idx = blockIdx.x * 256 + threadIdx.x;
    if (idx >= RR * NN) return;
    s_out[idx] = rsqrtf((float)max(deg_out[idx], 1));
    s_in [idx] = rsqrtf((float)max(deg_in [idx], 1));
}

// ---------------- 3-phase scan: deg_in -> row_ptr (exclusive, per relation) ----
__global__ __launch_bounds__(1024) void scan_reduce_kernel(
    const int* __restrict__ deg_in, int* __restrict__ bsum)
{
    const int r = blockIdx.x / NB;
    const int b = blockIdx.x % NB;
    const int t = threadIdx.x;
    const int* deg = deg_in + (size_t)r * NN;
    int n0 = b * SCAN_TILE + t * 4;
    int s = 0;
    if (n0 + 3 < NN) {
        int4 q = *reinterpret_cast<const int4*>(&deg[n0]);
        s = q.x + q.y + q.z + q.w;
    } else {
        for (int i = 0; i < 4; ++i) if (n0 + i < NN) s += deg[n0 + i];
    }
    __shared__ int sh[1024];
    sh[t] = s;
    __syncthreads();
    for (int off = 512; off > 0; off >>= 1) {
        if (t < off) sh[t] += sh[t + off];
        __syncthreads();
    }
    if (t == 0) bsum[blockIdx.x] = sh[0];
}

__global__ void scan_spine_kernel(int* __restrict__ bsum)
{
    if (threadIdx.x != 0) return;
    int r = blockIdx.x;
    int run = 0;
    for (int i = 0; i < NB; ++i) {
        int v = bsum[r * NB + i];
        bsum[r * NB + i] = run;
        run += v;
    }
}

__global__ __launch_bounds__(1024) void scan_final_kernel(
    const int* __restrict__ deg_in, const int* __restrict__ bsum,
    int* __restrict__ row_ptr)
{
    const int r = blockIdx.x / NB;
    const int b = blockIdx.x % NB;
    const int t = threadIdx.x;
    const int* deg = deg_in + (size_t)r * NN;
    int* rp = row_ptr + (size_t)r * (NN + 1);
    int n0 = b * SCAN_TILE + t * 4;
    int v[4] = {0, 0, 0, 0};
    if (n0 + 3 < NN) {
        int4 q = *reinterpret_cast<const int4*>(&deg[n0]);
        v[0] = q.x; v[1] = q.y; v[2] = q.z; v[3] = q.w;
    } else {
        for (int i = 0; i < 4; ++i) if (n0 + i < NN) v[i] = deg[n0 + i];
    }
    int s = v[0] + v[1] + v[2] + v[3];
    __shared__ int sh[1024];
    sh[t] = s;
    __syncthreads();
    for (int off = 1; off < 1024; off <<= 1) {
        int x = (t >= off) ? sh[t - off] : 0;
        __syncthreads();
        if (t >= off) sh[t] += x;
        __syncthreads();
    }
    int off = bsum[blockIdx.x] + sh[t] - s;
    for (int i = 0; i < 4; ++i) {
        if (n0 + i < NN) { rp[n0 + i] = off; off += v[i]; }
    }
    if (b == NB - 1 && t == 0) rp[NN] = EE;
}

// ---------------- CSR fill: col[] = src ids grouped by dst ----------------
__global__ __launch_bounds__(256) void fill_kernel(
    const int* __restrict__ src, const int* __restrict__ dst,
    const int* __restrict__ row_ptr, int* __restrict__ fill,
    int* __restrict__ col)
{
    int idx = blockIdx.x * 256 + threadIdx.x;
    if (idx >= RR * EE) return;
    int r = idx / EE;
    int d = dst[idx];
    int pos = row_ptr[(size_t)r * (NN + 1) + d] + atomicAdd(&fill[(size_t)r * NN + d], 1);
    col[(size_t)r * EE + pos] = src[idx];
}

// ---------------- weight transpose + bf16 convert: Wt[r][m][k] = bf16(W[r][k][m]) ----
__global__ __launch_bounds__(256) void convw_kernel(
    const float* __restrict__ W, unsigned short* __restrict__ Wt, int K, int M, int total)
{
    int idx = blockIdx.x * 256 + threadIdx.x;
    if (idx >= total) return;
    int r = idx / (K * M);
    int rem = idx - r * K * M;
    int k = rem / M;
    int m = rem - k * M;
    Wt[((size_t)r * M + m) * K + k] = (unsigned short)bf16round(W[idx]);
}

// ---------------- bf16 MFMA GEMM: C = diag(srow) * A @ Wt^T ----------
// BM=128, BK=32, 4 waves 2x2; 16x16x32 MFMA. A: f32 or bf16 (row scale fused);
// C: f32 or bf16.
template<int K, int BN, bool A_BF16, bool C_BF16>
__global__ __launch_bounds__(256) void gemm_bf16_kernel(
    const void* __restrict__ Av, const unsigned short* __restrict__ Wt,
    const float* __restrict__ srow, void* __restrict__ Cv, int N)
{
    constexpr int BM  = 128;
    constexpr int BK  = 32;
    constexpr int LDT = 56;            // 112 B row stride
    constexpr int MF  = 4;
    constexpr int NF  = BN / 32;

    __shared__ unsigned short As[BM * LDT];
    __shared__ unsigned short Bs[BN * LDT];

    const int tid  = threadIdx.x;
    const int wave = tid >> 6;
    const int lane = tid & 63;
    const int wr   = wave >> 1;
    const int wc   = wave & 1;
    const int row0 = blockIdx.x * BM;
    const int l15  = lane & 15;
    const int lq   = lane >> 4;

    f32x4 acc[MF][NF];
    #pragma unroll
    for (int mi = 0; mi < MF; ++mi)
        #pragma unroll
        for (int ni = 0; ni < NF; ++ni)
            #pragma unroll
            for (int q = 0; q < 4; ++q) acc[mi][ni][q] = 0.0f;

    for (int k0 = 0; k0 < K; k0 += BK) {
        if constexpr (!A_BF16) {
            const float* A = (const float*)Av;
            #pragma unroll
            for (int l = 0; l < 4; ++l) {              // 128 rows x 8 float4-chunks
                int c  = tid + l * 256;
                int r  = c >> 3;
                int kc = c & 7;
                float4 v = make_float4(0.f, 0.f, 0.f, 0.f);
                float sc = 0.f;
                if (row0 + r < N) {
                    v = *reinterpret_cast<const float4*>(&A[(size_t)(row0 + r) * K + k0 + kc * 4]);
                    sc = srow[row0 + r];
                }
                uint2 pk;
                pk.x = pack2_bf16(v.x * sc, v.y * sc);
                pk.y = pack2_bf16(v.z * sc, v.w * sc);
                *reinterpret_cast<uint2*>(&As[r * LDT + kc * 4]) = pk;
            }
        } else {
            const unsigned short* A = (const unsigned short*)Av;
            #pragma unroll
            for (int l = 0; l < 2; ++l) {              // 128 rows x 4 uint4-chunks (8 bf16)
                int c  = tid + l * 256;
                int r  = c >> 2;
                int kc = c & 3;
                uint4 u = make_uint4(0u, 0u, 0u, 0u);
                float sc = 0.f;
                if (row0 + r < N) {
                    u = *reinterpret_cast<const uint4*>(&A[(size_t)(row0 + r) * K + k0 + kc * 8]);
                    sc = srow[row0 + r];
                }
                uint4 o;
                o.x = pack2_bf16(__uint_as_float(u.x << 16) * sc, __uint_as_float(u.x & 0xFFFF0000u) * sc);
                o.y = pack2_bf16(__uint_as_float(u.y << 16) * sc, __uint_as_float(u.y & 0xFFFF0000u) * sc);
                o.z = pack2_bf16(__uint_as_float(u.z << 16) * sc, __uint_as_float(u.z & 0xFFFF0000u) * sc);
                o.w = pack2_bf16(__uint_as_float(u.w << 16) * sc, __uint_as_float(u.w & 0xFFFF0000u) * sc);
                *reinterpret_cast<uint4*>(&As[r * LDT + kc * 8]) = o;
            }
        }
        // ---- stage B tile: BN rows (n) x 32 k from Wt (bf16 [n][k]) ----
        #pragma unroll
        for (int l = 0; l < (BN * 4) / 256; ++l) {
            int c  = tid + l * 256;
            int r  = c >> 2;
            int kc = c & 3;
            *reinterpret_cast<uint4*>(&Bs[r * LDT + kc * 8]) =
                *reinterpret_cast<const uint4*>(&Wt[(size_t)r * K + k0 + kc * 8]);
        }
        __syncthreads();

        bf16x8 af[MF], bfg[NF];
        #pragma unroll
        for (int mi = 0; mi < MF; ++mi)
            af[mi] = *reinterpret_cast<const bf16x8*>(
                &As[(wr * 64 + mi * 16 + l15) * LDT + lq * 8]);
        #pragma unroll
        for (int ni = 0; ni < NF; ++ni)
            bfg[ni] = *reinterpret_cast<const bf16x8*>(
                &Bs[(wc * (BN / 2) + ni * 16 + l15) * LDT + lq * 8]);
        #pragma unroll
        for (int mi = 0; mi < MF; ++mi)
            #pragma unroll
            for (int ni = 0; ni < NF; ++ni)
                acc[mi][ni] = __builtin_amdgcn_mfma_f32_16x16x32_bf16(
                    af[mi], bfg[ni], acc[mi][ni], 0, 0, 0);
        __syncthreads();
    }

    // ---- write C: D layout col=lane&15, row=(lane>>4)*4+reg ----
    #pragma unroll
    for (int mi = 0; mi < MF; ++mi) {
        int rbase = row0 + wr * 64 + mi * 16 + lq * 4;
        #pragma unroll
        for (int ni = 0; ni < NF; ++ni) {
            int cc = wc * (BN / 2) + ni * 16 + l15;
            #pragma unroll
            for (int q = 0; q < 4; ++q) {
                int rr = rbase + q;
                if (rr < N) {
                    if constexpr (C_BF16)
                        ((unsigned short*)Cv)[(size_t)rr * BN + cc] =
                            (unsigned short)bf16round(acc[mi][ni][q]);
                    else
                        ((float*)Cv)[(size_t)rr * BN + cc] = acc[mi][ni][q];
                }
            }
        }
    }
}

// ---------------- merged gather layer 1: h1(bf16) = relu(mean_r(agg_r*s_in_r + b_r)) ----
// Y1: bf16-packed (uint = 2 feats), rows pre-scaled by s_out. One wave per node.
__global__ __launch_bounds__(256) void gather1_kernel(
    const unsigned* __restrict__ Y, const float* __restrict__ s_in,
    const float* __restrict__ b1, const int* __restrict__ row_ptr,
    const int* __restrict__ col, unsigned* __restrict__ h1)
{
    const int wid  = threadIdx.x >> 6;
    const int lane = threadIdx.x & 63;
    const int n    = blockIdx.x * 4 + wid;
    if (n >= NN) return;

    float ox = 0.f, oy = 0.f;
    #pragma unroll
    for (int r = 0; r < RR; ++r) {
        const int* rp = row_ptr + (size_t)r * (NN + 1);
        const int* cl = col + (size_t)r * EE;
        const unsigned* Yr = Y + (size_t)r * NN * 64;
        int beg = rp[n], end = rp[n + 1];
        float a0x = 0.f, a0y = 0.f, a1x = 0.f, a1y = 0.f;
        int e = beg;
        for (; e + 1 < end; e += 2) {
            int s0 = cl[e], s1 = cl[e + 1];
            unsigned u0 = Yr[(size_t)s0 * 64 + lane];
            unsigned u1 = Yr[(size_t)s1 * 64 + lane];
            a0x += __uint_as_float(u0 << 16);
            a0y += __uint_as_float(u0 & 0xFFFF0000u);
            a1x += __uint_as_float(u1 << 16);
            a1y += __uint_as_float(u1 & 0xFFFF0000u);
        }
        if (e < end) {
            unsigned u0 = Yr[(size_t)cl[e] * 64 + lane];
            a0x += __uint_as_float(u0 << 16);
            a0y += __uint_as_float(u0 & 0xFFFF0000u);
        }
        float si = s_in[(size_t)r * NN + n];
        float2 bb = *reinterpret_cast<const float2*>(&b1[(size_t)r * FHID + lane * 2]);
        ox = fmaf(a0x + a1x, si, ox) + bb.x;
        oy = fmaf(a0y + a1y, si, oy) + bb.y;
    }
    const float inv = 1.0f / (float)RR;
    ox = fmaxf(ox * inv, 0.f);
    oy = fmaxf(oy * inv, 0.f);
    h1[(size_t)n * 64 + lane] = pack2_bf16(ox, oy);
}

// ---------------- merged gather layer 2: h2(f32) = mean_r(agg_r*s_in_r + b_r) ----
__global__ __launch_bounds__(256) void gather2_kernel(
    const float* __restrict__ Y, const float* __restrict__ s_in,
    const float* __restrict__ b2, const int* __restrict__ row_ptr,
    const int* __restrict__ col, float* __restrict__ h2)
{
    const int wid  = threadIdx.x >> 6;
    const int lane = threadIdx.x & 63;
    const int n    = blockIdx.x * 4 + wid;
    if (n >= NN) return;

    float o = 0.f;
    #pragma unroll
    for (int r = 0; r < RR; ++r) {
        const int* rp = row_ptr + (size_t)r * (NN + 1);
        const int* cl = col + (size_t)r * EE;
        const float* Yr = Y + (size_t)r * NN * 64;
        int beg = rp[n], end = rp[n + 1];
        float a0 = 0.f, a1 = 0.f;
        int e = beg;
        for (; e + 1 < end; e += 2) {
            a0 += Yr[(size_t)cl[e] * 64 + lane];
            a1 += Yr[(size_t)cl[e + 1] * 64 + lane];
        }
        if (e < end) a0 += Yr[(size_t)cl[e] * 64 + lane];
        o = fmaf(a0 + a1, s_in[(size_t)r * NN + n], o) + b2[(size_t)r * FOUT + lane];
    }
    h2[(size_t)n * 64 + lane] = o * (1.0f / (float)RR);
}

// ---------------- edge dot-product scores ----------------
__global__ __launch_bounds__(256) void score_kernel(
    const float* __restrict__ h, const int* __restrict__ src0,
    const int* __restrict__ dst0, const int* __restrict__ nsrc,
    const int* __restrict__ ndst, float* __restrict__ out)
{
    int idx = blockIdx.x * 256 + threadIdx.x;  // grid exact: 2*E*16
    int e = idx >> 4;
    int l = idx & 15;
    int u, v;
    if (e < EE) { u = src0[e]; v = dst0[e]; }
    else        { u = nsrc[e - EE]; v = ndst[e - EE]; }
    float4 a  = *reinterpret_cast<const float4*>(&h[(size_t)u * FOUT + l * 4]);
    float4 bb = *reinterpret_cast<const float4*>(&h[(size_t)v * FOUT + l * 4]);
    float p = a.x * bb.x + a.y * bb.y + a.z * bb.z + a.w * bb.w;
    p += __shfl_xor(p, 8, 16);
    p += __shfl_xor(p, 4, 16);
    p += __shfl_xor(p, 2, 16);
    p += __shfl_xor(p, 1, 16);
    if (l == 0) out[e] = p;
}

// ---------------- launch ----------------
extern "C" void kernel_launch(void* const* d_in, const int* in_sizes, int n_in,
                              void* d_out, int out_size, void* d_ws, size_t ws_size,
                              hipStream_t stream)
{
    const float* feature = (const float*)d_in[0];
    const float* W1      = (const float*)d_in[1];
    const float* b1      = (const float*)d_in[2];
    const float* W2      = (const float*)d_in[3];
    const float* b2      = (const float*)d_in[4];
    const int*   src     = (const int*)d_in[5];
    const int*   dst     = (const int*)d_in[6];
    const int*   nsrc    = (const int*)d_in[7];
    const int*   ndst    = (const int*)d_in[8];
    float* out = (float*)d_out;

    // workspace layout (~168 MB); Y1(bf16) and Y2(f32) alias the same region
    char* p = (char*)d_ws;
    float* s_out   = (float*)p; p += sizeof(float) * RR * NN;
    float* s_in    = (float*)p; p += sizeof(float) * RR * NN;
    unsigned* h1   = (unsigned*)p; p += sizeof(unsigned) * (size_t)NN * 64;   // bf16x2
    float* h2      = (float*)p; p += sizeof(float) * (size_t)NN * FOUT;
    char*  Yu      = p;         p += (size_t)RR * NN * FHID * 2;              // 76.8 MB union
    int*   deg_out = (int*)p;   p += sizeof(int) * RR * NN;
    int*   deg_in  = (int*)p;   p += sizeof(int) * RR * NN;
    int*   row_ptr = (int*)p;   p += sizeof(int) * RR * (NN + 1);
    int*   fill    = (int*)p;   p += sizeof(int) * RR * NN;
    int*   col     = (int*)p;   p += sizeof(int) * (size_t)RR * EE;
    int*   bsum    = (int*)p;   p += sizeof(int) * RR * NB;
    unsigned short* Wt1 = (unsigned short*)p; p += sizeof(unsigned short) * RR * FIN * FHID;
    unsigned short* Wt2 = (unsigned short*)p; p += sizeof(unsigned short) * RR * FHID * FOUT;

    unsigned short* Y1 = (unsigned short*)Yu;                // R x N x 128 bf16
    float*          Y2 = (float*)Yu;                         // R x N x 64 f32 (aliases Y1)

    const int edge_grid = (RR * EE + 255) / 256;

    // ---- CSR build + degree scales + weight conversion ----
    hipMemsetAsync(deg_out, 0, sizeof(int) * 2 * RR * NN, stream);
    hipMemsetAsync(fill,    0, sizeof(int) * RR * NN, stream);
    count_deg_kernel<<<edge_grid, 256, 0, stream>>>(src, dst, deg_out, deg_in);
    finalize_deg_kernel<<<(RR * NN + 255) / 256, 256, 0, stream>>>(deg_out, deg_in, s_out, s_in);
    scan_reduce_kernel<<<RR * NB, 1024, 0, stream>>>(deg_in, bsum);
    scan_spine_kernel<<<RR, 64, 0, stream>>>(bsum);
    scan_final_kernel<<<RR * NB, 1024, 0, stream>>>(deg_in, bsum, row_ptr);
    fill_kernel<<<edge_grid, 256, 0, stream>>>(src, dst, row_ptr, fill, col);
    convw_kernel<<<(RR * FIN * FHID + 255) / 256, 256, 0, stream>>>(
        W1, Wt1, FIN, FHID, RR * FIN * FHID);
    convw_kernel<<<(RR * FHID * FOUT + 255) / 256, 256, 0, stream>>>(
        W2, Wt2, FHID, FOUT, RR * FHID * FOUT);

    const int gemm_grid = (NN + 127) / 128;
    const int node_grid = (NN + 3) / 4;

    // ---- layer 1: Y1_r = bf16(diag(s_out_r)*feature @ W1_r); h1 = relu(mean(...)) ----
    for (int r = 0; r < RR; ++r)
        gemm_bf16_kernel<FIN, FHID, false, true><<<gemm_grid, 256, 0, stream>>>(
            feature, Wt1 + (size_t)r * FIN * FHID, s_out + (size_t)r * NN,
            Y1 + (size_t)r * NN * FHID, NN);
    gather1_kernel<<<node_grid, 256, 0, stream>>>(
        (const unsigned*)Y1, s_in, b1, row_ptr, col, h1);

    // ---- layer 2: Y2_r = f32(diag(s_out_r)*h1 @ W2_r); h2 = mean(...) ----
    for (int r = 0; r < RR; ++r)
        gemm_bf16_kernel<FHID, FOUT, true, false><<<gemm_grid, 256, 0, stream>>>(
            h1, Wt2 + (size_t)r * FHID * FOUT, s_out + (size_t)r * NN,
            Y2 + (size_t)r * NN * FOUT, NN);
    gather2_kernel<<<node_grid, 256, 0, stream>>>(
        Y2, s_in, b2, row_ptr, col, h2);

    // ---- scores ----
    score_kernel<<<(2 * EE * 16) / 256, 256, 0, stream>>>(h2, src, dst, nsrc, ndst, out);
}

// Round 7
// 568.098 us; speedup vs baseline: 7.9727x; 1.1597x over previous
//
#include <hip/hip_runtime.h>

// ---- problem constants (match reference) ----
namespace {
constexpr int NN   = 100000;  // nodes
constexpr int RR   = 3;       // relations
constexpr int EE   = 500000;  // edges per relation
constexpr int FIN  = 256;
constexpr int FHID = 128;
constexpr int FOUT = 64;
constexpr int SCAN_TILE = 4096;                       // elems per scan block
constexpr int NB = (NN + SCAN_TILE - 1) / SCAN_TILE;  // 25 blocks per relation
// histogram-count geometry
constexpr int NCHUNK = 8;
constexpr int CH     = NN / NCHUNK;    // 12500 nodes/chunk -> 50 KB LDS
constexpr int GH     = 8;              // edge slices per (rel,chunk)
constexpr int SLICE  = EE / GH;        // 62500
}

typedef float f32x4  __attribute__((ext_vector_type(4)));
typedef short bf16x8 __attribute__((ext_vector_type(8)));

__device__ inline unsigned bf16round(float a) {
    unsigned u = __float_as_uint(a);
    return (u + 0x7FFFu + ((u >> 16) & 1u)) >> 16;   // RNE
}
__device__ inline unsigned pack2_bf16(float a, float b) {
    return bf16round(a) | (bf16round(b) << 16);
}

// ---------------- LDS-histogram degree count ----------------
// grid: 2(dir) x RR x NCHUNK x GH blocks, 512 threads.
// dir 0: dst -> partial_in ; dir 1: src -> partial_out. Non-atomic flush:
// partial[g][r][node] — (g,r,chunk) triples write disjoint ranges.
__global__ __launch_bounds__(512) void hist_deg_kernel(
    const int* __restrict__ src, const int* __restrict__ dst,
    int* __restrict__ partial_in, int* __restrict__ partial_out)
{
    __shared__ int cnt[CH];   // 50 KB
    const int b   = blockIdx.x;
    const int dir = b / (RR * NCHUNK * GH);
    const int rem = b % (RR * NCHUNK * GH);
    const int r   = rem / (NCHUNK * GH);
    const int c   = (rem / GH) % NCHUNK;
    const int g   = rem % GH;
    const int tid = threadIdx.x;

    for (int i = tid; i < CH; i += 512) cnt[i] = 0;
    __syncthreads();

    const int* ids = (dir ? src : dst) + (size_t)r * EE + (size_t)g * SLICE;
    const int base = c * CH;
    for (int i = tid; i < SLICE; i += 512) {
        int id = ids[i] - base;
        if ((unsigned)id < (unsigned)CH) atomicAdd(&cnt[id], 1);
    }
    __syncthreads();

    int* part = (dir ? partial_out : partial_in) + (size_t)g * RR * NN + (size_t)r * NN + base;
    for (int i = tid; i < CH; i += 512) part[i] = cnt[i];
}

// reduce partials -> deg_in + s_in (dir 0) / s_out (dir 1)
__global__ __launch_bounds__(256) void reduce_deg_kernel(
    const int* __restrict__ partial_in, const int* __restrict__ partial_out,
    int* __restrict__ deg_in, float* __restrict__ s_in, float* __restrict__ s_out)
{
    int idx = blockIdx.x * 256 + threadIdx.x;
    if (idx >= 2 * RR * NN) return;
    int dir = idx / (RR * NN);
    int j   = idx % (RR * NN);
    const int* part = dir ? partial_out : partial_in;
    int s = 0;
    #pragma unroll
    for (int g = 0; g < GH; ++g) s += part[(size_t)g * RR * NN + j];
    float v = rsqrtf((float)max(s, 1));
    if (dir == 0) { deg_in[j] = s; s_in[j] = v; }
    else          { s_out[j] = v; }
}

// ---------------- 3-phase scan: deg_in -> row_ptr (exclusive, per relation) ----
__global__ __launch_bounds__(1024) void scan_reduce_kernel(
    const int* __restrict__ deg_in, int* __restrict__ bsum)
{
    const int r = blockIdx.x / NB;
    const int b = blockIdx.x % NB;
    const int t = threadIdx.x;
    const int* deg = deg_in + (size_t)r * NN;
    int n0 = b * SCAN_TILE + t * 4;
    int s = 0;
    if (n0 + 3 < NN) {
        int4 q = *reinterpret_cast<const int4*>(&deg[n0]);
        s = q.x + q.y + q.z + q.w;
    } else {
        for (int i = 0; i < 4; ++i) if (n0 + i < NN) s += deg[n0 + i];
    }
    __shared__ int sh[1024];
    sh[t] = s;
    __syncthreads();
    for (int off = 512; off > 0; off >>= 1) {
        if (t < off) sh[t] += sh[t + off];
        __syncthreads();
    }
    if (t == 0) bsum[blockIdx.x] = sh[0];
}

__global__ void scan_spine_kernel(int* __restrict__ bsum)
{
    if (threadIdx.x != 0) return;
    int r = blockIdx.x;
    int run = 0;
    for (int i = 0; i < NB; ++i) {
        int v = bsum[r * NB + i];
        bsum[r * NB + i] = run;
        run += v;
    }
}

__global__ __launch_bounds__(1024) void scan_final_kernel(
    const int* __restrict__ deg_in, const int* __restrict__ bsum,
    int* __restrict__ row_ptr, int* __restrict__ cursor)
{
    const int r = blockIdx.x / NB;
    const int b = blockIdx.x % NB;
    const int t = threadIdx.x;
    const int* deg = deg_in + (size_t)r * NN;
    int* rp = row_ptr + (size_t)r * (NN + 1);
    int* cu = cursor  + (size_t)r * NN;
    int n0 = b * SCAN_TILE + t * 4;
    int v[4] = {0, 0, 0, 0};
    if (n0 + 3 < NN) {
        int4 q = *reinterpret_cast<const int4*>(&deg[n0]);
        v[0] = q.x; v[1] = q.y; v[2] = q.z; v[3] = q.w;
    } else {
        for (int i = 0; i < 4; ++i) if (n0 + i < NN) v[i] = deg[n0 + i];
    }
    int s = v[0] + v[1] + v[2] + v[3];
    __shared__ int sh[1024];
    sh[t] = s;
    __syncthreads();
    for (int off = 1; off < 1024; off <<= 1) {
        int x = (t >= off) ? sh[t - off] : 0;
        __syncthreads();
        if (t >= off) sh[t] += x;
        __syncthreads();
    }
    int off = bsum[blockIdx.x] + sh[t] - s;
    for (int i = 0; i < 4; ++i) {
        if (n0 + i < NN) { rp[n0 + i] = off; cu[n0 + i] = off; off += v[i]; }
    }
    if (b == NB - 1 && t == 0) rp[NN] = EE;
}

// ---------------- CSR fill: col[] = src ids grouped by dst (cursor = advancing copy) ----
__global__ __launch_bounds__(256) void fill_kernel(
    const int* __restrict__ src, const int* __restrict__ dst,
    int* __restrict__ cursor, int* __restrict__ col)
{
    int idx = blockIdx.x * 256 + threadIdx.x;
    if (idx >= RR * EE) return;
    int r = idx / EE;
    int d = dst[idx];
    int pos = atomicAdd(&cursor[(size_t)r * NN + d], 1);
    col[(size_t)r * EE + pos] = src[idx];
}

// ---------------- weight transpose + bf16 convert: Wt[r][m][k] = bf16(W[r][k][m]) ----
__global__ __launch_bounds__(256) void convw_kernel(
    const float* __restrict__ W, unsigned short* __restrict__ Wt, int K, int M, int total)
{
    int idx = blockIdx.x * 256 + threadIdx.x;
    if (idx >= total) return;
    int r = idx / (K * M);
    int rem = idx - r * K * M;
    int k = rem / M;
    int m = rem - k * M;
    Wt[((size_t)r * M + m) * K + k] = (unsigned short)bf16round(W[idx]);
}

// ---------------- bf16 MFMA GEMM: C_r = diag(srow_r) * A @ Wt_r^T, r = blockIdx.y ----
// BM=128, BK=32, 4 waves 2x2; 16x16x32 MFMA. A: f32 or bf16; C: f32 or bf16.
template<int K, int BN, bool A_BF16, bool C_BF16>
__global__ __launch_bounds__(256) void gemm_bf16_kernel(
    const void* __restrict__ Av, const unsigned short* __restrict__ Wt_base,
    const float* __restrict__ srow_base, void* __restrict__ Cv_base, int N)
{
    constexpr int BM  = 128;
    constexpr int BK  = 32;
    constexpr int LDT = 56;            // 112 B row stride
    constexpr int MF  = 4;
    constexpr int NF  = BN / 32;

    __shared__ unsigned short As[BM * LDT];
    __shared__ unsigned short Bs[BN * LDT];

    const int rrel = blockIdx.y;
    const unsigned short* Wt = Wt_base + (size_t)rrel * K * BN;
    const float* srow = srow_base + (size_t)rrel * NN;
    char* Cv = (char*)Cv_base + (size_t)rrel * NN * BN * (C_BF16 ? 2 : 4);

    const int tid  = threadIdx.x;
    const int wave = tid >> 6;
    const int lane = tid & 63;
    const int wr   = wave >> 1;
    const int wc   = wave & 1;
    const int row0 = blockIdx.x * BM;
    const int l15  = lane & 15;
    const int lq   = lane >> 4;

    f32x4 acc[MF][NF];
    #pragma unroll
    for (int mi = 0; mi < MF; ++mi)
        #pragma unroll
        for (int ni = 0; ni < NF; ++ni)
            #pragma unroll
            for (int q = 0; q < 4; ++q) acc[mi][ni][q] = 0.0f;

    for (int k0 = 0; k0 < K; k0 += BK) {
        if constexpr (!A_BF16) {
            const float* A = (const float*)Av;
            #pragma unroll
            for (int l = 0; l < 4; ++l) {              // 128 rows x 8 float4-chunks
                int c  = tid + l * 256;
                int r  = c >> 3;
                int kc = c & 7;
                float4 v = make_float4(0.f, 0.f, 0.f, 0.f);
                float sc = 0.f;
                if (row0 + r < N) {
                    v = *reinterpret_cast<const float4*>(&A[(size_t)(row0 + r) * K + k0 + kc * 4]);
                    sc = srow[row0 + r];
                }
                uint2 pk;
                pk.x = pack2_bf16(v.x * sc, v.y * sc);
                pk.y = pack2_bf16(v.z * sc, v.w * sc);
                *reinterpret_cast<uint2*>(&As[r * LDT + kc * 4]) = pk;
            }
        } else {
            const unsigned short* A = (const unsigned short*)Av;
            #pragma unroll
            for (int l = 0; l < 2; ++l) {              // 128 rows x 4 uint4-chunks (8 bf16)
                int c  = tid + l * 256;
                int r  = c >> 2;
                int kc = c & 3;
                uint4 u = make_uint4(0u, 0u, 0u, 0u);
                float sc = 0.f;
                if (row0 + r < N) {
                    u = *reinterpret_cast<const uint4*>(&A[(size_t)(row0 + r) * K + k0 + kc * 8]);
                    sc = srow[row0 + r];
                }
                uint4 o;
                o.x = pack2_bf16(__uint_as_float(u.x << 16) * sc, __uint_as_float(u.x & 0xFFFF0000u) * sc);
                o.y = pack2_bf16(__uint_as_float(u.y << 16) * sc, __uint_as_float(u.y & 0xFFFF0000u) * sc);
                o.z = pack2_bf16(__uint_as_float(u.z << 16) * sc, __uint_as_float(u.z & 0xFFFF0000u) * sc);
                o.w = pack2_bf16(__uint_as_float(u.w << 16) * sc, __uint_as_float(u.w & 0xFFFF0000u) * sc);
                *reinterpret_cast<uint4*>(&As[r * LDT + kc * 8]) = o;
            }
        }
        // ---- stage B tile: BN rows (n) x 32 k from Wt (bf16 [n][k]) ----
        #pragma unroll
        for (int l = 0; l < (BN * 4) / 256; ++l) {
            int c  = tid + l * 256;
            int r  = c >> 2;
            int kc = c & 3;
            *reinterpret_cast<uint4*>(&Bs[r * LDT + kc * 8]) =
                *reinterpret_cast<const uint4*>(&Wt[(size_t)r * K + k0 + kc * 8]);
        }
        __syncthreads();

        bf16x8 af[MF], bfg[NF];
        #pragma unroll
        for (int mi = 0; mi < MF; ++mi)
            af[mi] = *reinterpret_cast<const bf16x8*>(
                &As[(wr * 64 + mi * 16 + l15) * LDT + lq * 8]);
        #pragma unroll
        for (int ni = 0; ni < NF; ++ni)
            bfg[ni] = *reinterpret_cast<const bf16x8*>(
                &Bs[(wc * (BN / 2) + ni * 16 + l15) * LDT + lq * 8]);
        #pragma unroll
        for (int mi = 0; mi < MF; ++mi)
            #pragma unroll
            for (int ni = 0; ni < NF; ++ni)
                acc[mi][ni] = __builtin_amdgcn_mfma_f32_16x16x32_bf16(
                    af[mi], bfg[ni], acc[mi][ni], 0, 0, 0);
        __syncthreads();
    }

    // ---- write C: D layout col=lane&15, row=(lane>>4)*4+reg ----
    #pragma unroll
    for (int mi = 0; mi < MF; ++mi) {
        int rbase = row0 + wr * 64 + mi * 16 + lq * 4;
        #pragma unroll
        for (int ni = 0; ni < NF; ++ni) {
            int cc = wc * (BN / 2) + ni * 16 + l15;
            #pragma unroll
            for (int q = 0; q < 4; ++q) {
                int rr = rbase + q;
                if (rr < N) {
                    if constexpr (C_BF16)
                        ((unsigned short*)Cv)[(size_t)rr * BN + cc] =
                            (unsigned short)bf16round(acc[mi][ni][q]);
                    else
                        ((float*)Cv)[(size_t)rr * BN + cc] = acc[mi][ni][q];
                }
            }
        }
    }
}

// ---------------- merged gather layer 1: h1(bf16) = relu(mean_r(agg_r*s_in_r + b_r)) ----
__global__ __launch_bounds__(256) void gather1_kernel(
    const unsigned* __restrict__ Y, const float* __restrict__ s_in,
    const float* __restrict__ b1, const int* __restrict__ row_ptr,
    const int* __restrict__ col, unsigned* __restrict__ h1)
{
    const int wid  = threadIdx.x >> 6;
    const int lane = threadIdx.x & 63;
    const int n    = blockIdx.x * 4 + wid;
    if (n >= NN) return;

    float ox = 0.f, oy = 0.f;
    #pragma unroll
    for (int r = 0; r < RR; ++r) {
        const int* rp = row_ptr + (size_t)r * (NN + 1);
        const int* cl = col + (size_t)r * EE;
        const unsigned* Yr = Y + (size_t)r * NN * 64;
        int beg = rp[n], end = rp[n + 1];
        float a0x = 0.f, a0y = 0.f, a1x = 0.f, a1y = 0.f;
        int e = beg;
        for (; e + 1 < end; e += 2) {
            int s0 = cl[e], s1 = cl[e + 1];
            unsigned u0 = Yr[(size_t)s0 * 64 + lane];
            unsigned u1 = Yr[(size_t)s1 * 64 + lane];
            a0x += __uint_as_float(u0 << 16);
            a0y += __uint_as_float(u0 & 0xFFFF0000u);
            a1x += __uint_as_float(u1 << 16);
            a1y += __uint_as_float(u1 & 0xFFFF0000u);
        }
        if (e < end) {
            unsigned u0 = Yr[(size_t)cl[e] * 64 + lane];
            a0x += __uint_as_float(u0 << 16);
            a0y += __uint_as_float(u0 & 0xFFFF0000u);
        }
        float si = s_in[(size_t)r * NN + n];
        float2 bb = *reinterpret_cast<const float2*>(&b1[(size_t)r * FHID + lane * 2]);
        ox = fmaf(a0x + a1x, si, ox) + bb.x;
        oy = fmaf(a0y + a1y, si, oy) + bb.y;
    }
    const float inv = 1.0f / (float)RR;
    ox = fmaxf(ox * inv, 0.f);
    oy = fmaxf(oy * inv, 0.f);
    h1[(size_t)n * 64 + lane] = pack2_bf16(ox, oy);
}

// ---------------- merged gather layer 2: h2(f32) = mean_r(agg_r*s_in_r + b_r) ----
__global__ __launch_bounds__(256) void gather2_kernel(
    const float* __restrict__ Y, const float* __restrict__ s_in,
    const float* __restrict__ b2, const int* __restrict__ row_ptr,
    const int* __restrict__ col, float* __restrict__ h2)
{
    const int wid  = threadIdx.x >> 6;
    const int lane = threadIdx.x & 63;
    const int n    = blockIdx.x * 4 + wid;
    if (n >= NN) return;

    float o = 0.f;
    #pragma unroll
    for (int r = 0; r < RR; ++r) {
        const int* rp = row_ptr + (size_t)r * (NN + 1);
        const int* cl = col + (size_t)r * EE;
        const float* Yr = Y + (size_t)r * NN * 64;
        int beg = rp[n], end = rp[n + 1];
        float a0 = 0.f, a1 = 0.f;
        int e = beg;
        for (; e + 1 < end; e += 2) {
            a0 += Yr[(size_t)cl[e] * 64 + lane];
            a1 += Yr[(size_t)cl[e + 1] * 64 + lane];
        }
        if (e < end) a0 += Yr[(size_t)cl[e] * 64 + lane];
        o = fmaf(a0 + a1, s_in[(size_t)r * NN + n], o) + b2[(size_t)r * FOUT + lane];
    }
    h2[(size_t)n * 64 + lane] = o * (1.0f / (float)RR);
}

// ---------------- edge dot-product scores ----------------
__global__ __launch_bounds__(256) void score_kernel(
    const float* __restrict__ h, const int* __restrict__ src0,
    const int* __restrict__ dst0, const int* __restrict__ nsrc,
    const int* __restrict__ ndst, float* __restrict__ out)
{
    int idx = blockIdx.x * 256 + threadIdx.x;  // grid exact: 2*E*16
    int e = idx >> 4;
    int l = idx & 15;
    int u, v;
    if (e < EE) { u = src0[e]; v = dst0[e]; }
    else        { u = nsrc[e - EE]; v = ndst[e - EE]; }
    float4 a  = *reinterpret_cast<const float4*>(&h[(size_t)u * FOUT + l * 4]);
    float4 bb = *reinterpret_cast<const float4*>(&h[(size_t)v * FOUT + l * 4]);
    float p = a.x * bb.x + a.y * bb.y + a.z * bb.z + a.w * bb.w;
    p += __shfl_xor(p, 8, 16);
    p += __shfl_xor(p, 4, 16);
    p += __shfl_xor(p, 2, 16);
    p += __shfl_xor(p, 1, 16);
    if (l == 0) out[e] = p;
}

// ---------------- launch ----------------
extern "C" void kernel_launch(void* const* d_in, const int* in_sizes, int n_in,
                              void* d_out, int out_size, void* d_ws, size_t ws_size,
                              hipStream_t stream)
{
    const float* feature = (const float*)d_in[0];
    const float* W1      = (const float*)d_in[1];
    const float* b1      = (const float*)d_in[2];
    const float* W2      = (const float*)d_in[3];
    const float* b2      = (const float*)d_in[4];
    const int*   src     = (const int*)d_in[5];
    const int*   dst     = (const int*)d_in[6];
    const int*   nsrc    = (const int*)d_in[7];
    const int*   ndst    = (const int*)d_in[8];
    float* out = (float*)d_out;

    // workspace layout (~140 MB); Yu is a union: deg partials (CSR build phase),
    // then Y1(bf16) / Y2(f32)
    char* p = (char*)d_ws;
    float* s_out   = (float*)p; p += sizeof(float) * RR * NN;
    float* s_in    = (float*)p; p += sizeof(float) * RR * NN;
    unsigned* h1   = (unsigned*)p; p += sizeof(unsigned) * (size_t)NN * 64;   // bf16x2
    float* h2      = (float*)p; p += sizeof(float) * (size_t)NN * FOUT;
    char*  Yu      = p;         p += (size_t)RR * NN * FHID * 2;              // 76.8 MB union
    int*   deg_in  = (int*)p;   p += sizeof(int) * RR * NN;
    int*   row_ptr = (int*)p;   p += sizeof(int) * RR * (NN + 1);
    int*   cursor  = (int*)p;   p += sizeof(int) * RR * NN;
    int*   col     = (int*)p;   p += sizeof(int) * (size_t)RR * EE;
    int*   bsum    = (int*)p;   p += sizeof(int) * RR * NB;
    unsigned short* Wt1 = (unsigned short*)p; p += sizeof(unsigned short) * RR * FIN * FHID;
    unsigned short* Wt2 = (unsigned short*)p; p += sizeof(unsigned short) * RR * FHID * FOUT;

    unsigned short* Y1 = (unsigned short*)Yu;                // R x N x 128 bf16
    float*          Y2 = (float*)Yu;                         // R x N x 64 f32 (aliases Y1)
    int* partial_in  = (int*)Yu;                             // GH x R x N (9.6 MB)
    int* partial_out = partial_in + (size_t)GH * RR * NN;    // GH x R x N (9.6 MB)

    const int edge_grid = (RR * EE + 255) / 256;

    // ---- CSR build + degree scales + weight conversion (no global atomics for count) ----
    convw_kernel<<<(RR * FIN * FHID + 255) / 256, 256, 0, stream>>>(
        W1, Wt1, FIN, FHID, RR * FIN * FHID);
    convw_kernel<<<(RR * FHID * FOUT + 255) / 256, 256, 0, stream>>>(
        W2, Wt2, FHID, FOUT, RR * FHID * FOUT);
    hist_deg_kernel<<<2 * RR * NCHUNK * GH, 512, 0, stream>>>(
        src, dst, partial_in, partial_out);
    reduce_deg_kernel<<<(2 * RR * NN + 255) / 256, 256, 0, stream>>>(
        partial_in, partial_out, deg_in, s_in, s_out);
    scan_reduce_kernel<<<RR * NB, 1024, 0, stream>>>(deg_in, bsum);
    scan_spine_kernel<<<RR, 64, 0, stream>>>(bsum);
    scan_final_kernel<<<RR * NB, 1024, 0, stream>>>(deg_in, bsum, row_ptr, cursor);
    fill_kernel<<<edge_grid, 256, 0, stream>>>(src, dst, cursor, col);

    const dim3 gemm_grid((NN + 127) / 128, RR);
    const int node_grid = (NN + 3) / 4;

    // ---- layer 1: Y1_r = bf16(diag(s_out_r)*feature @ W1_r); h1 = relu(mean(...)) ----
    gemm_bf16_kernel<FIN, FHID, false, true><<<gemm_grid, 256, 0, stream>>>(
        feature, Wt1, s_out, Y1, NN);
    gather1_kernel<<<node_grid, 256, 0, stream>>>(
        (const unsigned*)Y1, s_in, b1, row_ptr, col, h1);

    // ---- layer 2: Y2_r = f32(diag(s_out_r)*h1 @ W2_r); h2 = mean(...) ----
    gemm_bf16_kernel<FHID, FOUT, true, false><<<gemm_grid, 256, 0, stream>>>(
        h1, Wt2, s_out, Y2, NN);
    gather2_kernel<<<node_grid, 256, 0, stream>>>(
        Y2, s_in, b2, row_ptr, col, h2);

    // ---- scores ----
    score_kernel<<<(2 * EE * 16) / 256, 256, 0, stream>>>(h2, src, dst, nsrc, ndst, out);
}

// Round 8
// 516.440 us; speedup vs baseline: 8.7702x; 1.1000x over previous
//
#include <hip/hip_runtime.h>

// ---- problem constants (match reference) ----
namespace {
constexpr int NN   = 100000;  // nodes
constexpr int RR   = 3;       // relations
constexpr int EE   = 500000;  // edges per relation
constexpr int FIN  = 256;
constexpr int FHID = 128;
constexpr int FOUT = 64;
constexpr int SCAN_TILE = 4096;                       // elems per scan block
constexpr int NB = (NN + SCAN_TILE - 1) / SCAN_TILE;  // 25 blocks per relation
// histogram-count geometry
constexpr int NCHUNK = 8;
constexpr int CH     = NN / NCHUNK;    // 12500 nodes/chunk -> 50 KB LDS
constexpr int GH     = 8;              // edge slices per (rel,chunk)
constexpr int SLICE  = EE / GH;        // 62500
}

typedef float f32x4  __attribute__((ext_vector_type(4)));
typedef short bf16x8 __attribute__((ext_vector_type(8)));

__device__ inline unsigned bf16round(float a) {
    unsigned u = __float_as_uint(a);
    return (u + 0x7FFFu + ((u >> 16) & 1u)) >> 16;   // RNE
}
__device__ inline unsigned pack2_bf16(float a, float b) {
    return bf16round(a) | (bf16round(b) << 16);
}

// ---------------- LDS-histogram degree count ----------------
// grid: 2(dir) x RR x NCHUNK x GH blocks, 512 threads.
// dir 0: dst -> partial_in ; dir 1: src -> partial_out. Non-atomic flush.
__global__ __launch_bounds__(512) void hist_deg_kernel(
    const int* __restrict__ src, const int* __restrict__ dst,
    int* __restrict__ partial_in, int* __restrict__ partial_out)
{
    __shared__ int cnt[CH];   // 50 KB
    const int b   = blockIdx.x;
    const int dir = b / (RR * NCHUNK * GH);
    const int rem = b % (RR * NCHUNK * GH);
    const int r   = rem / (NCHUNK * GH);
    const int c   = (rem / GH) % NCHUNK;
    const int g   = rem % GH;
    const int tid = threadIdx.x;

    for (int i = tid; i < CH; i += 512) cnt[i] = 0;
    __syncthreads();

    const int* ids = (dir ? src : dst) + (size_t)r * EE + (size_t)g * SLICE;
    const int base = c * CH;
    for (int i = tid; i < SLICE; i += 512) {
        int id = ids[i] - base;
        if ((unsigned)id < (unsigned)CH) atomicAdd(&cnt[id], 1);
    }
    __syncthreads();

    int* part = (dir ? partial_out : partial_in) + (size_t)g * RR * NN + (size_t)r * NN + base;
    for (int i = tid; i < CH; i += 512) part[i] = cnt[i];
}

// reduce partials -> deg_in + s_in (dir 0) / s_out (dir 1)
__global__ __launch_bounds__(256) void reduce_deg_kernel(
    const int* __restrict__ partial_in, const int* __restrict__ partial_out,
    int* __restrict__ deg_in, float* __restrict__ s_in, float* __restrict__ s_out)
{
    int idx = blockIdx.x * 256 + threadIdx.x;
    if (idx >= 2 * RR * NN) return;
    int dir = idx / (RR * NN);
    int j   = idx % (RR * NN);
    const int* part = dir ? partial_out : partial_in;
    int s = 0;
    #pragma unroll
    for (int g = 0; g < GH; ++g) s += part[(size_t)g * RR * NN + j];
    float v = rsqrtf((float)max(s, 1));
    if (dir == 0) { deg_in[j] = s; s_in[j] = v; }
    else          { s_out[j] = v; }
}

// ---------------- 3-phase scan: deg_in -> row_ptr (exclusive, per relation) ----
__global__ __launch_bounds__(1024) void scan_reduce_kernel(
    const int* __restrict__ deg_in, int* __restrict__ bsum)
{
    const int r = blockIdx.x / NB;
    const int b = blockIdx.x % NB;
    const int t = threadIdx.x;
    const int* deg = deg_in + (size_t)r * NN;
    int n0 = b * SCAN_TILE + t * 4;
    int s = 0;
    if (n0 + 3 < NN) {
        int4 q = *reinterpret_cast<const int4*>(&deg[n0]);
        s = q.x + q.y + q.z + q.w;
    } else {
        for (int i = 0; i < 4; ++i) if (n0 + i < NN) s += deg[n0 + i];
    }
    __shared__ int sh[1024];
    sh[t] = s;
    __syncthreads();
    for (int off = 512; off > 0; off >>= 1) {
        if (t < off) sh[t] += sh[t + off];
        __syncthreads();
    }
    if (t == 0) bsum[blockIdx.x] = sh[0];
}

__global__ void scan_spine_kernel(int* __restrict__ bsum)
{
    if (threadIdx.x != 0) return;
    int r = blockIdx.x;
    int run = 0;
    for (int i = 0; i < NB; ++i) {
        int v = bsum[r * NB + i];
        bsum[r * NB + i] = run;
        run += v;
    }
}

__global__ __launch_bounds__(1024) void scan_final_kernel(
    const int* __restrict__ deg_in, const int* __restrict__ bsum,
    int* __restrict__ row_ptr)
{
    const int r = blockIdx.x / NB;
    const int b = blockIdx.x % NB;
    const int t = threadIdx.x;
    const int* deg = deg_in + (size_t)r * NN;
    int* rp = row_ptr + (size_t)r * (NN + 1);
    int n0 = b * SCAN_TILE + t * 4;
    int v[4] = {0, 0, 0, 0};
    if (n0 + 3 < NN) {
        int4 q = *reinterpret_cast<const int4*>(&deg[n0]);
        v[0] = q.x; v[1] = q.y; v[2] = q.z; v[3] = q.w;
    } else {
        for (int i = 0; i < 4; ++i) if (n0 + i < NN) v[i] = deg[n0 + i];
    }
    int s = v[0] + v[1] + v[2] + v[3];
    __shared__ int sh[1024];
    sh[t] = s;
    __syncthreads();
    for (int off = 1; off < 1024; off <<= 1) {
        int x = (t >= off) ? sh[t - off] : 0;
        __syncthreads();
        if (t >= off) sh[t] += x;
        __syncthreads();
    }
    int off = bsum[blockIdx.x] + sh[t] - s;
    for (int i = 0; i < 4; ++i) {
        if (n0 + i < NN) { rp[n0 + i] = off; off += v[i]; }
    }
    if (b == NB - 1 && t == 0) rp[NN] = EE;
}

// ---------------- per-slice start offsets: partial_in[g][r][n] -> slice cursor base ----
__global__ __launch_bounds__(256) void slice_off_kernel(
    const int* __restrict__ row_ptr, int* __restrict__ partial_in)
{
    int idx = blockIdx.x * 256 + threadIdx.x;
    if (idx >= RR * NN) return;
    int r = idx / NN;
    int n = idx % NN;
    int base = row_ptr[(size_t)r * (NN + 1) + n];
    #pragma unroll
    for (int g = 0; g < GH; ++g) {
        size_t o = (size_t)g * RR * NN + idx;
        int p = partial_in[o];
        partial_in[o] = base;
        base += p;
    }
}

// ---------------- atomic-free CSR fill (LDS cursors per chunk+slice) ----------------
__global__ __launch_bounds__(512) void fill2_kernel(
    const int* __restrict__ src, const int* __restrict__ dst,
    const int* __restrict__ slice_off, int* __restrict__ col)
{
    __shared__ int cur[CH];   // 50 KB
    const int b   = blockIdx.x;               // r * NCHUNK*GH + c * GH + g
    const int r   = b / (NCHUNK * GH);
    const int c   = (b / GH) % NCHUNK;
    const int g   = b % GH;
    const int tid = threadIdx.x;
    const int base = c * CH;

    const int* so = slice_off + (size_t)g * RR * NN + (size_t)r * NN + base;
    for (int i = tid; i < CH; i += 512) cur[i] = so[i];
    __syncthreads();

    const int* ds = dst + (size_t)r * EE + (size_t)g * SLICE;
    const int* ss = src + (size_t)r * EE + (size_t)g * SLICE;
    int* cl = col + (size_t)r * EE;
    for (int i = tid; i < SLICE; i += 512) {
        int d = ds[i] - base;
        int s = ss[i];
        if ((unsigned)d < (unsigned)CH) {
            int pos = atomicAdd(&cur[d], 1);
            cl[pos] = s;
        }
    }
}

// ---------------- weight transpose + bf16 convert: Wt[r][m][k] = bf16(W[r][k][m]) ----
__global__ __launch_bounds__(256) void convw_kernel(
    const float* __restrict__ W, unsigned short* __restrict__ Wt, int K, int M, int total)
{
    int idx = blockIdx.x * 256 + threadIdx.x;
    if (idx >= total) return;
    int r = idx / (K * M);
    int rem = idx - r * K * M;
    int k = rem / M;
    int m = rem - k * M;
    Wt[((size_t)r * M + m) * K + k] = (unsigned short)bf16round(W[idx]);
}

// ---------------- bf16 MFMA GEMM: C_r = diag(srow_r) * A @ Wt_r^T, r = blockIdx.y ----
template<int K, int BN, bool A_BF16, bool C_BF16>
__global__ __launch_bounds__(256) void gemm_bf16_kernel(
    const void* __restrict__ Av, const unsigned short* __restrict__ Wt_base,
    const float* __restrict__ srow_base, void* __restrict__ Cv_base, int N)
{
    constexpr int BM  = 128;
    constexpr int BK  = 32;
    constexpr int LDT = 56;            // 112 B row stride
    constexpr int MF  = 4;
    constexpr int NF  = BN / 32;

    __shared__ unsigned short As[BM * LDT];
    __shared__ unsigned short Bs[BN * LDT];

    const int rrel = blockIdx.y;
    const unsigned short* Wt = Wt_base + (size_t)rrel * K * BN;
    const float* srow = srow_base + (size_t)rrel * NN;
    char* Cv = (char*)Cv_base + (size_t)rrel * NN * BN * (C_BF16 ? 2 : 4);

    const int tid  = threadIdx.x;
    const int wave = tid >> 6;
    const int lane = tid & 63;
    const int wr   = wave >> 1;
    const int wc   = wave & 1;
    const int row0 = blockIdx.x * BM;
    const int l15  = lane & 15;
    const int lq   = lane >> 4;

    f32x4 acc[MF][NF];
    #pragma unroll
    for (int mi = 0; mi < MF; ++mi)
        #pragma unroll
        for (int ni = 0; ni < NF; ++ni)
            #pragma unroll
            for (int q = 0; q < 4; ++q) acc[mi][ni][q] = 0.0f;

    for (int k0 = 0; k0 < K; k0 += BK) {
        if constexpr (!A_BF16) {
            const float* A = (const float*)Av;
            #pragma unroll
            for (int l = 0; l < 4; ++l) {              // 128 rows x 8 float4-chunks
                int c  = tid + l * 256;
                int r  = c >> 3;
                int kc = c & 7;
                float4 v = make_float4(0.f, 0.f, 0.f, 0.f);
                float sc = 0.f;
                if (row0 + r < N) {
                    v = *reinterpret_cast<const float4*>(&A[(size_t)(row0 + r) * K + k0 + kc * 4]);
                    sc = srow[row0 + r];
                }
                uint2 pk;
                pk.x = pack2_bf16(v.x * sc, v.y * sc);
                pk.y = pack2_bf16(v.z * sc, v.w * sc);
                *reinterpret_cast<uint2*>(&As[r * LDT + kc * 4]) = pk;
            }
        } else {
            const unsigned short* A = (const unsigned short*)Av;
            #pragma unroll
            for (int l = 0; l < 2; ++l) {              // 128 rows x 4 uint4-chunks (8 bf16)
                int c  = tid + l * 256;
                int r  = c >> 2;
                int kc = c & 3;
                uint4 u = make_uint4(0u, 0u, 0u, 0u);
                float sc = 0.f;
                if (row0 + r < N) {
                    u = *reinterpret_cast<const uint4*>(&A[(size_t)(row0 + r) * K + k0 + kc * 8]);
                    sc = srow[row0 + r];
                }
                uint4 o;
                o.x = pack2_bf16(__uint_as_float(u.x << 16) * sc, __uint_as_float(u.x & 0xFFFF0000u) * sc);
                o.y = pack2_bf16(__uint_as_float(u.y << 16) * sc, __uint_as_float(u.y & 0xFFFF0000u) * sc);
                o.z = pack2_bf16(__uint_as_float(u.z << 16) * sc, __uint_as_float(u.z & 0xFFFF0000u) * sc);
                o.w = pack2_bf16(__uint_as_float(u.w << 16) * sc, __uint_as_float(u.w & 0xFFFF0000u) * sc);
                *reinterpret_cast<uint4*>(&As[r * LDT + kc * 8]) = o;
            }
        }
        // ---- stage B tile: BN rows (n) x 32 k from Wt (bf16 [n][k]) ----
        #pragma unroll
        for (int l = 0; l < (BN * 4) / 256; ++l) {
            int c  = tid + l * 256;
            int r  = c >> 2;
            int kc = c & 3;
            *reinterpret_cast<uint4*>(&Bs[r * LDT + kc * 8]) =
                *reinterpret_cast<const uint4*>(&Wt[(size_t)r * K + k0 + kc * 8]);
        }
        __syncthreads();

        bf16x8 af[MF], bfg[NF];
        #pragma unroll
        for (int mi = 0; mi < MF; ++mi)
            af[mi] = *reinterpret_cast<const bf16x8*>(
                &As[(wr * 64 + mi * 16 + l15) * LDT + lq * 8]);
        #pragma unroll
        for (int ni = 0; ni < NF; ++ni)
            bfg[ni] = *reinterpret_cast<const bf16x8*>(
                &Bs[(wc * (BN / 2) + ni * 16 + l15) * LDT + lq * 8]);
        #pragma unroll
        for (int mi = 0; mi < MF; ++mi)
            #pragma unroll
            for (int ni = 0; ni < NF; ++ni)
                acc[mi][ni] = __builtin_amdgcn_mfma_f32_16x16x32_bf16(
                    af[mi], bfg[ni], acc[mi][ni], 0, 0, 0);
        __syncthreads();
    }

    // ---- write C: D layout col=lane&15, row=(lane>>4)*4+reg ----
    #pragma unroll
    for (int mi = 0; mi < MF; ++mi) {
        int rbase = row0 + wr * 64 + mi * 16 + lq * 4;
        #pragma unroll
        for (int ni = 0; ni < NF; ++ni) {
            int cc = wc * (BN / 2) + ni * 16 + l15;
            #pragma unroll
            for (int q = 0; q < 4; ++q) {
                int rr = rbase + q;
                if (rr < N) {
                    if constexpr (C_BF16)
                        ((unsigned short*)Cv)[(size_t)rr * BN + cc] =
                            (unsigned short)bf16round(acc[mi][ni][q]);
                    else
                        ((float*)Cv)[(size_t)rr * BN + cc] = acc[mi][ni][q];
                }
            }
        }
    }
}

// ---------------- merged gather layer 1 (4-way ILP): h1(bf16) ----------------
__global__ __launch_bounds__(256) void gather1_kernel(
    const unsigned* __restrict__ Y, const float* __restrict__ s_in,
    const float* __restrict__ b1, const int* __restrict__ row_ptr,
    const int* __restrict__ col, unsigned* __restrict__ h1)
{
    const int wid  = threadIdx.x >> 6;
    const int lane = threadIdx.x & 63;
    const int n    = blockIdx.x * 4 + wid;
    if (n >= NN) return;

    float ox = 0.f, oy = 0.f;
    #pragma unroll
    for (int r = 0; r < RR; ++r) {
        const int* rp = row_ptr + (size_t)r * (NN + 1);
        const int* cl = col + (size_t)r * EE;
        const unsigned* Yr = Y + (size_t)r * NN * 64;
        int beg = rp[n], end = rp[n + 1];
        float a0x = 0.f, a0y = 0.f, a1x = 0.f, a1y = 0.f;
        float a2x = 0.f, a2y = 0.f, a3x = 0.f, a3y = 0.f;
        int e = beg;
        for (; e + 3 < end; e += 4) {
            int s0 = cl[e], s1 = cl[e + 1], s2 = cl[e + 2], s3 = cl[e + 3];
            unsigned u0 = Yr[(size_t)s0 * 64 + lane];
            unsigned u1 = Yr[(size_t)s1 * 64 + lane];
            unsigned u2 = Yr[(size_t)s2 * 64 + lane];
            unsigned u3 = Yr[(size_t)s3 * 64 + lane];
            a0x += __uint_as_float(u0 << 16);
            a0y += __uint_as_float(u0 & 0xFFFF0000u);
            a1x += __uint_as_float(u1 << 16);
            a1y += __uint_as_float(u1 & 0xFFFF0000u);
            a2x += __uint_as_float(u2 << 16);
            a2y += __uint_as_float(u2 & 0xFFFF0000u);
            a3x += __uint_as_float(u3 << 16);
            a3y += __uint_as_float(u3 & 0xFFFF0000u);
        }
        for (; e < end; ++e) {
            unsigned u0 = Yr[(size_t)cl[e] * 64 + lane];
            a0x += __uint_as_float(u0 << 16);
            a0y += __uint_as_float(u0 & 0xFFFF0000u);
        }
        float si = s_in[(size_t)r * NN + n];
        float2 bb = *reinterpret_cast<const float2*>(&b1[(size_t)r * FHID + lane * 2]);
        ox = fmaf((a0x + a1x) + (a2x + a3x), si, ox) + bb.x;
        oy = fmaf((a0y + a1y) + (a2y + a3y), si, oy) + bb.y;
    }
    const float inv = 1.0f / (float)RR;
    ox = fmaxf(ox * inv, 0.f);
    oy = fmaxf(oy * inv, 0.f);
    h1[(size_t)n * 64 + lane] = pack2_bf16(ox, oy);
}

// ---------------- merged gather layer 2 (4-way ILP): h2(f32) ----------------
__global__ __launch_bounds__(256) void gather2_kernel(
    const float* __restrict__ Y, const float* __restrict__ s_in,
    const float* __restrict__ b2, const int* __restrict__ row_ptr,
    const int* __restrict__ col, float* __restrict__ h2)
{
    const int wid  = threadIdx.x >> 6;
    const int lane = threadIdx.x & 63;
    const int n    = blockIdx.x * 4 + wid;
    if (n >= NN) return;

    float o = 0.f;
    #pragma unroll
    for (int r = 0; r < RR; ++r) {
        const int* rp = row_ptr + (size_t)r * (NN + 1);
        const int* cl = col + (size_t)r * EE;
        const float* Yr = Y + (size_t)r * NN * 64;
        int beg = rp[n], end = rp[n + 1];
        float a0 = 0.f, a1 = 0.f, a2 = 0.f, a3 = 0.f;
        int e = beg;
        for (; e + 3 < end; e += 4) {
            a0 += Yr[(size_t)cl[e] * 64 + lane];
            a1 += Yr[(size_t)cl[e + 1] * 64 + lane];
            a2 += Yr[(size_t)cl[e + 2] * 64 + lane];
            a3 += Yr[(size_t)cl[e + 3] * 64 + lane];
        }
        for (; e < end; ++e) a0 += Yr[(size_t)cl[e] * 64 + lane];
        o = fmaf((a0 + a1) + (a2 + a3), s_in[(size_t)r * NN + n], o) + b2[(size_t)r * FOUT + lane];
    }
    h2[(size_t)n * 64 + lane] = o * (1.0f / (float)RR);
}

// ---------------- edge dot-product scores ----------------
__global__ __launch_bounds__(256) void score_kernel(
    const float* __restrict__ h, const int* __restrict__ src0,
    const int* __restrict__ dst0, const int* __restrict__ nsrc,
    const int* __restrict__ ndst, float* __restrict__ out)
{
    int idx = blockIdx.x * 256 + threadIdx.x;  // grid exact: 2*E*16
    int e = idx >> 4;
    int l = idx & 15;
    int u, v;
    if (e < EE) { u = src0[e]; v = dst0[e]; }
    else        { u = nsrc[e - EE]; v = ndst[e - EE]; }
    float4 a  = *reinterpret_cast<const float4*>(&h[(size_t)u * FOUT + l * 4]);
    float4 bb = *reinterpret_cast<const float4*>(&h[(size_t)v * FOUT + l * 4]);
    float p = a.x * bb.x + a.y * bb.y + a.z * bb.z + a.w * bb.w;
    p += __shfl_xor(p, 8, 16);
    p += __shfl_xor(p, 4, 16);
    p += __shfl_xor(p, 2, 16);
    p += __shfl_xor(p, 1, 16);
    if (l == 0) out[e] = p;
}

// ---------------- launch ----------------
extern "C" void kernel_launch(void* const* d_in, const int* in_sizes, int n_in,
                              void* d_out, int out_size, void* d_ws, size_t ws_size,
                              hipStream_t stream)
{
    const float* feature = (const float*)d_in[0];
    const float* W1      = (const float*)d_in[1];
    const float* b1      = (const float*)d_in[2];
    const float* W2      = (const float*)d_in[3];
    const float* b2      = (const float*)d_in[4];
    const int*   src     = (const int*)d_in[5];
    const int*   dst     = (const int*)d_in[6];
    const int*   nsrc    = (const int*)d_in[7];
    const int*   ndst    = (const int*)d_in[8];
    float* out = (float*)d_out;

    // workspace layout (~140 MB); Yu is a union: deg partials (CSR build phase),
    // then Y1(bf16) / Y2(f32)
    char* p = (char*)d_ws;
    float* s_out   = (float*)p; p += sizeof(float) * RR * NN;
    float* s_in    = (float*)p; p += sizeof(float) * RR * NN;
    unsigned* h1   = (unsigned*)p; p += sizeof(unsigned) * (size_t)NN * 64;   // bf16x2
    float* h2      = (float*)p; p += sizeof(float) * (size_t)NN * FOUT;
    char*  Yu      = p;         p += (size_t)RR * NN * FHID * 2;              // 76.8 MB union
    int*   deg_in  = (int*)p;   p += sizeof(int) * RR * NN;
    int*   row_ptr = (int*)p;   p += sizeof(int) * RR * (NN + 1);
    int*   col     = (int*)p;   p += sizeof(int) * (size_t)RR * EE;
    int*   bsum    = (int*)p;   p += sizeof(int) * RR * NB;
    unsigned short* Wt1 = (unsigned short*)p; p += sizeof(unsigned short) * RR * FIN * FHID;
    unsigned short* Wt2 = (unsigned short*)p; p += sizeof(unsigned short) * RR * FHID * FOUT;

    unsigned short* Y1 = (unsigned short*)Yu;                // R x N x 128 bf16
    float*          Y2 = (float*)Yu;                         // R x N x 64 f32 (aliases Y1)
    int* partial_in  = (int*)Yu;                             // GH x R x N (9.6 MB)
    int* partial_out = partial_in + (size_t)GH * RR * NN;    // GH x R x N (9.6 MB)

    // ---- CSR build + degree scales + weight conversion (no global atomics) ----
    convw_kernel<<<(RR * FIN * FHID + 255) / 256, 256, 0, stream>>>(
        W1, Wt1, FIN, FHID, RR * FIN * FHID);
    convw_kernel<<<(RR * FHID * FOUT + 255) / 256, 256, 0, stream>>>(
        W2, Wt2, FHID, FOUT, RR * FHID * FOUT);
    hist_deg_kernel<<<2 * RR * NCHUNK * GH, 512, 0, stream>>>(
        src, dst, partial_in, partial_out);
    reduce_deg_kernel<<<(2 * RR * NN + 255) / 256, 256, 0, stream>>>(
        partial_in, partial_out, deg_in, s_in, s_out);
    scan_reduce_kernel<<<RR * NB, 1024, 0, stream>>>(deg_in, bsum);
    scan_spine_kernel<<<RR, 64, 0, stream>>>(bsum);
    scan_final_kernel<<<RR * NB, 1024, 0, stream>>>(deg_in, bsum, row_ptr);
    slice_off_kernel<<<(RR * NN + 255) / 256, 256, 0, stream>>>(row_ptr, partial_in);
    fill2_kernel<<<RR * NCHUNK * GH, 512, 0, stream>>>(src, dst, partial_in, col);

    const dim3 gemm_grid((NN + 127) / 128, RR);
    const int node_grid = (NN + 3) / 4;

    // ---- layer 1: Y1_r = bf16(diag(s_out_r)*feature @ W1_r); h1 = relu(mean(...)) ----
    gemm_bf16_kernel<FIN, FHID, false, true><<<gemm_grid, 256, 0, stream>>>(
        feature, Wt1, s_out, Y1, NN);
    gather1_kernel<<<node_grid, 256, 0, stream>>>(
        (const unsigned*)Y1, s_in, b1, row_ptr, col, h1);

    // ---- layer 2: Y2_r = f32(diag(s_out_r)*h1 @ W2_r); h2 = mean(...) ----
    gemm_bf16_kernel<FHID, FOUT, true, false><<<gemm_grid, 256, 0, stream>>>(
        h1, Wt2, s_out, Y2, NN);
    gather2_kernel<<<node_grid, 256, 0, stream>>>(
        Y2, s_in, b2, row_ptr, col, h2);

    // ---- scores ----
    score_kernel<<<(2 * EE * 16) / 256, 256, 0, stream>>>(h2, src, dst, nsrc, ndst, out);
}

// Round 9
// 513.270 us; speedup vs baseline: 8.8243x; 1.0062x over previous
//
#include <hip/hip_runtime.h>

// ---- problem constants (match reference) ----
namespace {
constexpr int NN   = 100000;  // nodes
constexpr int RR   = 3;       // relations
constexpr int EE   = 500000;  // edges per relation
constexpr int FIN  = 256;
constexpr int FHID = 128;
constexpr int FOUT = 64;
constexpr int SCAN_TILE = 4096;                       // elems per scan block
constexpr int NB = (NN + SCAN_TILE - 1) / SCAN_TILE;  // 25 blocks per relation
// histogram-count geometry
constexpr int NCHUNK = 8;
constexpr int CH     = NN / NCHUNK;    // 12500 nodes/chunk -> 50 KB LDS
constexpr int GH     = 8;              // edge slices per (rel,chunk)
constexpr int SLICE  = EE / GH;        // 62500
}

typedef float f32x4  __attribute__((ext_vector_type(4)));
typedef short bf16x8 __attribute__((ext_vector_type(8)));

__device__ inline unsigned bf16round(float a) {
    unsigned u = __float_as_uint(a);
    return (u + 0x7FFFu + ((u >> 16) & 1u)) >> 16;   // RNE
}
__device__ inline unsigned pack2_bf16(float a, float b) {
    return bf16round(a) | (bf16round(b) << 16);
}

// ---------------- LDS-histogram degree count ----------------
__global__ __launch_bounds__(512) void hist_deg_kernel(
    const int* __restrict__ src, const int* __restrict__ dst,
    int* __restrict__ partial_in, int* __restrict__ partial_out)
{
    __shared__ int cnt[CH];   // 50 KB
    const int b   = blockIdx.x;
    const int dir = b / (RR * NCHUNK * GH);
    const int rem = b % (RR * NCHUNK * GH);
    const int r   = rem / (NCHUNK * GH);
    const int c   = (rem / GH) % NCHUNK;
    const int g   = rem % GH;
    const int tid = threadIdx.x;

    for (int i = tid; i < CH; i += 512) cnt[i] = 0;
    __syncthreads();

    const int* ids = (dir ? src : dst) + (size_t)r * EE + (size_t)g * SLICE;
    const int base = c * CH;
    for (int i = tid; i < SLICE; i += 512) {
        int id = ids[i] - base;
        if ((unsigned)id < (unsigned)CH) atomicAdd(&cnt[id], 1);
    }
    __syncthreads();

    int* part = (dir ? partial_out : partial_in) + (size_t)g * RR * NN + (size_t)r * NN + base;
    for (int i = tid; i < CH; i += 512) part[i] = cnt[i];
}

// reduce partials -> deg_in + s_in (dir 0) / s_out (dir 1)
__global__ __launch_bounds__(256) void reduce_deg_kernel(
    const int* __restrict__ partial_in, const int* __restrict__ partial_out,
    int* __restrict__ deg_in, float* __restrict__ s_in, float* __restrict__ s_out)
{
    int idx = blockIdx.x * 256 + threadIdx.x;
    if (idx >= 2 * RR * NN) return;
    int dir = idx / (RR * NN);
    int j   = idx % (RR * NN);
    const int* part = dir ? partial_out : partial_in;
    int s = 0;
    #pragma unroll
    for (int g = 0; g < GH; ++g) s += part[(size_t)g * RR * NN + j];
    float v = rsqrtf((float)max(s, 1));
    if (dir == 0) { deg_in[j] = s; s_in[j] = v; }
    else          { s_out[j] = v; }
}

// ---------------- 3-phase scan: deg_in -> row_ptr (exclusive, per relation) ----
__global__ __launch_bounds__(1024) void scan_reduce_kernel(
    const int* __restrict__ deg_in, int* __restrict__ bsum)
{
    const int r = blockIdx.x / NB;
    const int b = blockIdx.x % NB;
    const int t = threadIdx.x;
    const int* deg = deg_in + (size_t)r * NN;
    int n0 = b * SCAN_TILE + t * 4;
    int s = 0;
    if (n0 + 3 < NN) {
        int4 q = *reinterpret_cast<const int4*>(&deg[n0]);
        s = q.x + q.y + q.z + q.w;
    } else {
        for (int i = 0; i < 4; ++i) if (n0 + i < NN) s += deg[n0 + i];
    }
    __shared__ int sh[1024];
    sh[t] = s;
    __syncthreads();
    for (int off = 512; off > 0; off >>= 1) {
        if (t < off) sh[t] += sh[t + off];
        __syncthreads();
    }
    if (t == 0) bsum[blockIdx.x] = sh[0];
}

__global__ void scan_spine_kernel(int* __restrict__ bsum)
{
    if (threadIdx.x != 0) return;
    int r = blockIdx.x;
    int run = 0;
    for (int i = 0; i < NB; ++i) {
        int v = bsum[r * NB + i];
        bsum[r * NB + i] = run;
        run += v;
    }
}

__global__ __launch_bounds__(1024) void scan_final_kernel(
    const int* __restrict__ deg_in, const int* __restrict__ bsum,
    int* __restrict__ row_ptr)
{
    const int r = blockIdx.x / NB;
    const int b = blockIdx.x % NB;
    const int t = threadIdx.x;
    const int* deg = deg_in + (size_t)r * NN;
    int* rp = row_ptr + (size_t)r * (NN + 1);
    int n0 = b * SCAN_TILE + t * 4;
    int v[4] = {0, 0, 0, 0};
    if (n0 + 3 < NN) {
        int4 q = *reinterpret_cast<const int4*>(&deg[n0]);
        v[0] = q.x; v[1] = q.y; v[2] = q.z; v[3] = q.w;
    } else {
        for (int i = 0; i < 4; ++i) if (n0 + i < NN) v[i] = deg[n0 + i];
    }
    int s = v[0] + v[1] + v[2] + v[3];
    __shared__ int sh[1024];
    sh[t] = s;
    __syncthreads();
    for (int off = 1; off < 1024; off <<= 1) {
        int x = (t >= off) ? sh[t - off] : 0;
        __syncthreads();
        if (t >= off) sh[t] += x;
        __syncthreads();
    }
    int off = bsum[blockIdx.x] + sh[t] - s;
    for (int i = 0; i < 4; ++i) {
        if (n0 + i < NN) { rp[n0 + i] = off; off += v[i]; }
    }
    if (b == NB - 1 && t == 0) rp[NN] = EE;
}

// ---------------- per-slice start offsets: partial_in[g][r][n] -> slice cursor base ----
__global__ __launch_bounds__(256) void slice_off_kernel(
    const int* __restrict__ row_ptr, int* __restrict__ partial_in)
{
    int idx = blockIdx.x * 256 + threadIdx.x;
    if (idx >= RR * NN) return;
    int r = idx / NN;
    int n = idx % NN;
    int base = row_ptr[(size_t)r * (NN + 1) + n];
    #pragma unroll
    for (int g = 0; g < GH; ++g) {
        size_t o = (size_t)g * RR * NN + idx;
        int p = partial_in[o];
        partial_in[o] = base;
        base += p;
    }
}

// ---------------- atomic-free CSR fill (LDS cursors per chunk+slice) ----------------
__global__ __launch_bounds__(512) void fill2_kernel(
    const int* __restrict__ src, const int* __restrict__ dst,
    const int* __restrict__ slice_off, int* __restrict__ col)
{
    __shared__ int cur[CH];   // 50 KB
    const int b   = blockIdx.x;               // r * NCHUNK*GH + c * GH + g
    const int r   = b / (NCHUNK * GH);
    const int c   = (b / GH) % NCHUNK;
    const int g   = b % GH;
    const int tid = threadIdx.x;
    const int base = c * CH;

    const int* so = slice_off + (size_t)g * RR * NN + (size_t)r * NN + base;
    for (int i = tid; i < CH; i += 512) cur[i] = so[i];
    __syncthreads();

    const int* ds = dst + (size_t)r * EE + (size_t)g * SLICE;
    const int* ss = src + (size_t)r * EE + (size_t)g * SLICE;
    int* cl = col + (size_t)r * EE;
    for (int i = tid; i < SLICE; i += 512) {
        int d = ds[i] - base;
        int s = ss[i];
        if ((unsigned)d < (unsigned)CH) {
            int pos = atomicAdd(&cur[d], 1);
            cl[pos] = s;
        }
    }
}

// ---------------- weight transpose + bf16 convert: Wt[r][m][k] = bf16(W[r][k][m]) ----
__global__ __launch_bounds__(256) void convw_kernel(
    const float* __restrict__ W, unsigned short* __restrict__ Wt, int K, int M, int total)
{
    int idx = blockIdx.x * 256 + threadIdx.x;
    if (idx >= total) return;
    int r = idx / (K * M);
    int rem = idx - r * K * M;
    int k = rem / M;
    int m = rem - k * M;
    Wt[((size_t)r * M + m) * K + k] = (unsigned short)bf16round(W[idx]);
}

// ---------------- A-slab-resident bf16 MFMA GEMM ----------------
// One block owns 128 rows; A slab staged ONCE in LDS (bf16, unscaled); loop over
// relations inside: stage 10(5) KB B tile per k-step, MFMA, epilogue applies
// per-row scale s_out_r. C_r = diag(s_r) * A @ Wt_r^T.
template<int K, int BN, bool A_BF16, bool C_BF16>
__global__ __launch_bounds__(256) void gemm_slab_kernel(
    const void* __restrict__ Av, const unsigned short* __restrict__ Wt_base,
    const float* __restrict__ srow_base, void* __restrict__ Cv_base, int N)
{
    constexpr int BM  = 128;
    constexpr int BK  = 32;
    constexpr int LDA = K + 8;     // +16B pad: 4-bank shift/row -> <=2-way conflicts
    constexpr int LDB = BK + 8;
    constexpr int MF  = 4;
    constexpr int NF  = BN / 32;

    __shared__ unsigned short As[BM * LDA];   // 67.6 KB (K=256) / 34.8 KB (K=128)
    __shared__ unsigned short Bs[BN * LDB];   // 10 KB (BN=128) / 5 KB (BN=64)
    __shared__ float sLds[RR * BM];           // 1.5 KB

    const int tid  = threadIdx.x;
    const int wave = tid >> 6;
    const int lane = tid & 63;
    const int wr   = wave >> 1;
    const int wc   = wave & 1;
    const int row0 = blockIdx.x * BM;
    const int l15  = lane & 15;
    const int lq   = lane >> 4;

    // ---- stage per-row scales for all relations ----
    for (int i = tid; i < RR * BM; i += 256) {
        int r  = i / BM;
        int rr = row0 + (i % BM);
        sLds[i] = (rr < N) ? srow_base[(size_t)r * NN + rr] : 0.f;
    }

    // ---- stage A slab (unscaled bf16) ----
    if constexpr (!A_BF16) {
        const float* A = (const float*)Av;
        constexpr int CPR = K / 4;             // float4 chunks per row
        for (int c = tid; c < BM * CPR; c += 256) {
            int row = c / CPR, kc = c % CPR;
            float4 v = make_float4(0.f, 0.f, 0.f, 0.f);
            if (row0 + row < N)
                v = *reinterpret_cast<const float4*>(&A[(size_t)(row0 + row) * K + kc * 4]);
            uint2 pk;
            pk.x = pack2_bf16(v.x, v.y);
            pk.y = pack2_bf16(v.z, v.w);
            *reinterpret_cast<uint2*>(&As[row * LDA + kc * 4]) = pk;
        }
    } else {
        const unsigned short* A = (const unsigned short*)Av;
        constexpr int CPR = K / 8;             // uint4 chunks per row
        for (int c = tid; c < BM * CPR; c += 256) {
            int row = c / CPR, kc = c % CPR;
            uint4 v = make_uint4(0u, 0u, 0u, 0u);
            if (row0 + row < N)
                v = *reinterpret_cast<const uint4*>(&A[(size_t)(row0 + row) * K + kc * 8]);
            *reinterpret_cast<uint4*>(&As[row * LDA + kc * 8]) = v;
        }
    }

    for (int r = 0; r < RR; ++r) {
        const unsigned short* Wt = Wt_base + (size_t)r * BN * K;

        f32x4 acc[MF][NF];
        #pragma unroll
        for (int mi = 0; mi < MF; ++mi)
            #pragma unroll
            for (int ni = 0; ni < NF; ++ni)
                #pragma unroll
                for (int q = 0; q < 4; ++q) acc[mi][ni][q] = 0.0f;

        for (int k0 = 0; k0 < K; k0 += BK) {
            __syncthreads();   // protects Bs (and As/sLds on first pass / epilogue)
            for (int c = tid; c < BN * (BK / 8); c += 256) {
                int n = c >> 2, kc = c & 3;
                *reinterpret_cast<uint4*>(&Bs[n * LDB + kc * 8]) =
                    *reinterpret_cast<const uint4*>(&Wt[(size_t)n * K + k0 + kc * 8]);
            }
            __syncthreads();

            bf16x8 af[MF], bfg[NF];
            #pragma unroll
            for (int mi = 0; mi < MF; ++mi)
                af[mi] = *reinterpret_cast<const bf16x8*>(
                    &As[(wr * 64 + mi * 16 + l15) * LDA + k0 + lq * 8]);
            #pragma unroll
            for (int ni = 0; ni < NF; ++ni)
                bfg[ni] = *reinterpret_cast<const bf16x8*>(
                    &Bs[(wc * (BN / 2) + ni * 16 + l15) * LDB + lq * 8]);
            #pragma unroll
            for (int mi = 0; mi < MF; ++mi)
                #pragma unroll
                for (int ni = 0; ni < NF; ++ni)
                    acc[mi][ni] = __builtin_amdgcn_mfma_f32_16x16x32_bf16(
                        af[mi], bfg[ni], acc[mi][ni], 0, 0, 0);
        }

        // ---- epilogue: scale rows by s_out_r, write C ----
        char* Cv = (char*)Cv_base + (size_t)r * NN * BN * (C_BF16 ? 2 : 4);
        #pragma unroll
        for (int mi = 0; mi < MF; ++mi) {
            int lrow = wr * 64 + mi * 16 + lq * 4;
            #pragma unroll
            for (int ni = 0; ni < NF; ++ni) {
                int cc = wc * (BN / 2) + ni * 16 + l15;
                #pragma unroll
                for (int q = 0; q < 4; ++q) {
                    int rr = row0 + lrow + q;
                    if (rr < N) {
                        float val = acc[mi][ni][q] * sLds[r * BM + lrow + q];
                        if constexpr (C_BF16)
                            ((unsigned short*)Cv)[(size_t)rr * BN + cc] =
                                (unsigned short)bf16round(val);
                        else
                            ((float*)Cv)[(size_t)rr * BN + cc] = val;
                    }
                }
            }
        }
    }
}

// ---------------- merged gather layer 1 (4-way ILP): h1(bf16) ----------------
__global__ __launch_bounds__(256) void gather1_kernel(
    const unsigned* __restrict__ Y, const float* __restrict__ s_in,
    const float* __restrict__ b1, const int* __restrict__ row_ptr,
    const int* __restrict__ col, unsigned* __restrict__ h1)
{
    const int wid  = threadIdx.x >> 6;
    const int lane = threadIdx.x & 63;
    const int n    = blockIdx.x * 4 + wid;
    if (n >= NN) return;

    float ox = 0.f, oy = 0.f;
    #pragma unroll
    for (int r = 0; r < RR; ++r) {
        const int* rp = row_ptr + (size_t)r * (NN + 1);
        const int* cl = col + (size_t)r * EE;
        const unsigned* Yr = Y + (size_t)r * NN * 64;
        int beg = rp[n], end = rp[n + 1];
        float a0x = 0.f, a0y = 0.f, a1x = 0.f, a1y = 0.f;
        float a2x = 0.f, a2y = 0.f, a3x = 0.f, a3y = 0.f;
        int e = beg;
        for (; e + 3 < end; e += 4) {
            int s0 = cl[e], s1 = cl[e + 1], s2 = cl[e + 2], s3 = cl[e + 3];
            unsigned u0 = Yr[(size_t)s0 * 64 + lane];
            unsigned u1 = Yr[(size_t)s1 * 64 + lane];
            unsigned u2 = Yr[(size_t)s2 * 64 + lane];
            unsigned u3 = Yr[(size_t)s3 * 64 + lane];
            a0x += __uint_as_float(u0 << 16);
            a0y += __uint_as_float(u0 & 0xFFFF0000u);
            a1x += __uint_as_float(u1 << 16);
            a1y += __uint_as_float(u1 & 0xFFFF0000u);
            a2x += __uint_as_float(u2 << 16);
            a2y += __uint_as_float(u2 & 0xFFFF0000u);
            a3x += __uint_as_float(u3 << 16);
            a3y += __uint_as_float(u3 & 0xFFFF0000u);
        }
        for (; e < end; ++e) {
            unsigned u0 = Yr[(size_t)cl[e] * 64 + lane];
            a0x += __uint_as_float(u0 << 16);
            a0y += __uint_as_float(u0 & 0xFFFF0000u);
        }
        float si = s_in[(size_t)r * NN + n];
        float2 bb = *reinterpret_cast<const float2*>(&b1[(size_t)r * FHID + lane * 2]);
        ox = fmaf((a0x + a1x) + (a2x + a3x), si, ox) + bb.x;
        oy = fmaf((a0y + a1y) + (a2y + a3y), si, oy) + bb.y;
    }
    const float inv = 1.0f / (float)RR;
    ox = fmaxf(ox * inv, 0.f);
    oy = fmaxf(oy * inv, 0.f);
    h1[(size_t)n * 64 + lane] = pack2_bf16(ox, oy);
}

// ---------------- merged gather layer 2 (4-way ILP, bf16 Y2): h2(f32) ----------------
__global__ __launch_bounds__(256) void gather2_kernel(
    const unsigned short* __restrict__ Y, const float* __restrict__ s_in,
    const float* __restrict__ b2, const int* __restrict__ row_ptr,
    const int* __restrict__ col, float* __restrict__ h2)
{
    const int wid  = threadIdx.x >> 6;
    const int lane = threadIdx.x & 63;
    const int n    = blockIdx.x * 4 + wid;
    if (n >= NN) return;

    float o = 0.f;
    #pragma unroll
    for (int r = 0; r < RR; ++r) {
        const int* rp = row_ptr + (size_t)r * (NN + 1);
        const int* cl = col + (size_t)r * EE;
        const unsigned short* Yr = Y + (size_t)r * NN * 64;
        int beg = rp[n], end = rp[n + 1];
        float a0 = 0.f, a1 = 0.f, a2 = 0.f, a3 = 0.f;
        int e = beg;
        for (; e + 3 < end; e += 4) {
            a0 += __uint_as_float((unsigned)Yr[(size_t)cl[e] * 64 + lane] << 16);
            a1 += __uint_as_float((unsigned)Yr[(size_t)cl[e + 1] * 64 + lane] << 16);
            a2 += __uint_as_float((unsigned)Yr[(size_t)cl[e + 2] * 64 + lane] << 16);
            a3 += __uint_as_float((unsigned)Yr[(size_t)cl[e + 3] * 64 + lane] << 16);
        }
        for (; e < end; ++e)
            a0 += __uint_as_float((unsigned)Yr[(size_t)cl[e] * 64 + lane] << 16);
        o = fmaf((a0 + a1) + (a2 + a3), s_in[(size_t)r * NN + n], o) + b2[(size_t)r * FOUT + lane];
    }
    h2[(size_t)n * 64 + lane] = o * (1.0f / (float)RR);
}

// ---------------- edge dot-product scores ----------------
__global__ __launch_bounds__(256) void score_kernel(
    const float* __restrict__ h, const int* __restrict__ src0,
    const int* __restrict__ dst0, const int* __restrict__ nsrc,
    const int* __restrict__ ndst, float* __restrict__ out)
{
    int idx = blockIdx.x * 256 + threadIdx.x;  // grid exact: 2*E*16
    int e = idx >> 4;
    int l = idx & 15;
    int u, v;
    if (e < EE) { u = src0[e]; v = dst0[e]; }
    else        { u = nsrc[e - EE]; v = ndst[e - EE]; }
    float4 a  = *reinterpret_cast<const float4*>(&h[(size_t)u * FOUT + l * 4]);
    float4 bb = *reinterpret_cast<const float4*>(&h[(size_t)v * FOUT + l * 4]);
    float p = a.x * bb.x + a.y * bb.y + a.z * bb.z + a.w * bb.w;
    p += __shfl_xor(p, 8, 16);
    p += __shfl_xor(p, 4, 16);
    p += __shfl_xor(p, 2, 16);
    p += __shfl_xor(p, 1, 16);
    if (l == 0) out[e] = p;
}

// ---------------- launch ----------------
extern "C" void kernel_launch(void* const* d_in, const int* in_sizes, int n_in,
                              void* d_out, int out_size, void* d_ws, size_t ws_size,
                              hipStream_t stream)
{
    const float* feature = (const float*)d_in[0];
    const float* W1      = (const float*)d_in[1];
    const float* b1      = (const float*)d_in[2];
    const float* W2      = (const float*)d_in[3];
    const float* b2      = (const float*)d_in[4];
    const int*   src     = (const int*)d_in[5];
    const int*   dst     = (const int*)d_in[6];
    const int*   nsrc    = (const int*)d_in[7];
    const int*   ndst    = (const int*)d_in[8];
    float* out = (float*)d_out;

    // workspace layout (~140 MB); Yu union: deg partials -> Y1(bf16) -> Y2(bf16)
    char* p = (char*)d_ws;
    float* s_out   = (float*)p; p += sizeof(float) * RR * NN;
    float* s_in    = (float*)p; p += sizeof(float) * RR * NN;
    unsigned* h1   = (unsigned*)p; p += sizeof(unsigned) * (size_t)NN * 64;   // bf16x2
    float* h2      = (float*)p; p += sizeof(float) * (size_t)NN * FOUT;
    char*  Yu      = p;         p += (size_t)RR * NN * FHID * 2;              // 76.8 MB union
    int*   deg_in  = (int*)p;   p += sizeof(int) * RR * NN;
    int*   row_ptr = (int*)p;   p += sizeof(int) * RR * (NN + 1);
    int*   col     = (int*)p;   p += sizeof(int) * (size_t)RR * EE;
    int*   bsum    = (int*)p;   p += sizeof(int) * RR * NB;
    unsigned short* Wt1 = (unsigned short*)p; p += sizeof(unsigned short) * RR * FIN * FHID;
    unsigned short* Wt2 = (unsigned short*)p; p += sizeof(unsigned short) * RR * FHID * FOUT;

    unsigned short* Y1 = (unsigned short*)Yu;                // R x N x 128 bf16
    unsigned short* Y2 = (unsigned short*)Yu;                // R x N x 64 bf16 (aliases Y1)
    int* partial_in  = (int*)Yu;                             // GH x R x N (9.6 MB)
    int* partial_out = partial_in + (size_t)GH * RR * NN;    // GH x R x N (9.6 MB)

    // ---- CSR build + degree scales + weight conversion (no global atomics) ----
    convw_kernel<<<(RR * FIN * FHID + 255) / 256, 256, 0, stream>>>(
        W1, Wt1, FIN, FHID, RR * FIN * FHID);
    convw_kernel<<<(RR * FHID * FOUT + 255) / 256, 256, 0, stream>>>(
        W2, Wt2, FHID, FOUT, RR * FHID * FOUT);
    hist_deg_kernel<<<2 * RR * NCHUNK * GH, 512, 0, stream>>>(
        src, dst, partial_in, partial_out);
    reduce_deg_kernel<<<(2 * RR * NN + 255) / 256, 256, 0, stream>>>(
        partial_in, partial_out, deg_in, s_in, s_out);
    scan_reduce_kernel<<<RR * NB, 1024, 0, stream>>>(deg_in, bsum);
    scan_spine_kernel<<<RR, 64, 0, stream>>>(bsum);
    scan_final_kernel<<<RR * NB, 1024, 0, stream>>>(deg_in, bsum, row_ptr);
    slice_off_kernel<<<(RR * NN + 255) / 256, 256, 0, stream>>>(row_ptr, partial_in);
    fill2_kernel<<<RR * NCHUNK * GH, 512, 0, stream>>>(src, dst, partial_in, col);

    const int gemm_grid = (NN + 127) / 128;
    const int node_grid = (NN + 3) / 4;

    // ---- layer 1: Y1_r = bf16(diag(s_out_r)*feature @ W1_r); h1 = relu(mean(...)) ----
    gemm_slab_kernel<FIN, FHID, false, true><<<gemm_grid, 256, 0, stream>>>(
        feature, Wt1, s_out, Y1, NN);
    gather1_kernel<<<node_grid, 256, 0, stream>>>(
        (const unsigned*)Y1, s_in, b1, row_ptr, col, h1);

    // ---- layer 2: Y2_r = bf16(diag(s_out_r)*h1 @ W2_r); h2 = mean(...) ----
    gemm_slab_kernel<FHID, FOUT, true, true><<<gemm_grid, 256, 0, stream>>>(
        h1, Wt2, s_out, Y2, NN);
    gather2_kernel<<<node_grid, 256, 0, stream>>>(
        Y2, s_in, b2, row_ptr, col, h2);

    // ---- scores ----
    score_kernel<<<(2 * EE * 16) / 256, 256, 0, stream>>>(h2, src, dst, nsrc, ndst, out);
}